// Round 4
// baseline (369.387 us; speedup 1.0000x reference)
//
#include <hip/hip_runtime.h>
#include <hip/hip_bf16.h>

// Problem constants
#define BATCH 32
#define CIN   1024
#define HW    784     // 28*28
#define WIMG  28
#define PADW  30      // padded 30x30 plane
#define PADHW 900
#define P1    256
#define P2    256
#define P3    1024
#define NFLAT (BATCH * HW)   // 25088 = 196 * 128 = 392 * 64 exactly

typedef __attribute__((ext_vector_type(8))) short bfrag_t;          // 8 bf16 (4 VGPRs)
typedef __attribute__((ext_vector_type(8))) unsigned short usvec8;
typedef __attribute__((ext_vector_type(4))) unsigned short usvec4;
typedef __attribute__((ext_vector_type(4))) float accvec_t;

static __device__ __forceinline__ unsigned short f2bf(float f) {
    union { __hip_bfloat16 h; unsigned short u; } cv;
    cv.h = __float2bfloat16(f);
    return cv.u;
}
static __device__ __forceinline__ float bf2f(unsigned short u) {
    union { float f; unsigned int i; } cv;
    cv.i = ((unsigned int)u) << 16;
    return cv.f;
}

// async 16B global->LDS DMA. LDS dest is wave-uniform base + lane*16B.
#define GLDS16(g, l) __builtin_amdgcn_global_load_lds(                      \
        (const __attribute__((address_space(1))) void*)(g),                 \
        (__attribute__((address_space(3))) void*)(l), 16, 0, 0)

// barrier WITHOUT compiler-inserted vmcnt(0) drain; pinned against code motion
#define RAW_BARRIER() do {                         \
        __builtin_amdgcn_sched_barrier(0);         \
        __builtin_amdgcn_s_barrier();              \
        __builtin_amdgcn_sched_barrier(0);         \
    } while (0)
#define WAITCNT_VM(N) do {                                        \
        asm volatile("s_waitcnt vmcnt(" #N ")" ::: "memory");     \
        __builtin_amdgcn_sched_barrier(0);                        \
    } while (0)

// ---------------- pre-pass: transpose perm_dconv -> permT[p][c] ----------------
__global__ __launch_bounds__(256) void permT_kernel(const int* __restrict__ perm,
                                                    int* __restrict__ permT) {
    int p = blockIdx.x, c = threadIdx.x;
    permT[p * P1 + c] = perm[c * HW + p];
}

// ---------------- pre-pass: pack weights to bf16 ----------------
// w1b[m][k]; w3b[m][k]; wdb[r][m][k] = bf16(wd[m][k][r])
__global__ __launch_bounds__(256) void pack_weights_kernel(
        const float* __restrict__ w1, const float* __restrict__ wd,
        const float* __restrict__ w3, unsigned short* __restrict__ w1b,
        unsigned short* __restrict__ wdb, unsigned short* __restrict__ w3b) {
    int i = blockIdx.x * 256 + threadIdx.x;
    if (i < 262144) w1b[i] = f2bf(w1[i]);
    int i2 = i - 262144;
    if (i2 >= 0 && i2 < 262144) w3b[i2] = f2bf(w3[i2]);
    int i3 = i - 524288;
    if (i3 >= 0 && i3 < 589824) {
        int m = i3 / 2304, rem = i3 - m * 2304;
        int k = rem / 9, r = rem - k * 9;
        wdb[((size_t)r * P2 + m) * P1 + k] = f2bf(wd[i3]);
    }
}

// ---------------- pre-pass: transpose x -> xt[n][c] bf16, n = b*HW+hw ----------------
__global__ __launch_bounds__(256) void transpose_x_kernel(const float* __restrict__ x,
                                                          unsigned short* __restrict__ xt) {
    __shared__ __align__(16) unsigned short T[64 * 72];   // [hw_local][c_local], stride 72
    const int c0 = blockIdx.x * 64;
    const int n0 = blockIdx.y * 64;
    const int t  = threadIdx.x;
    const int f  = t & 15;          // hw-quad index: hw_local = 4f..4f+3
    const int cg = t >> 4;          // channel group: c_local = 4cg..4cg+3
    const int n  = n0 + f * 4;
    const int b  = n / HW, hw = n - b * HW;       // float4 never straddles b (784 % 4 == 0)
    const float* xb = x + ((size_t)b * CIN + c0 + cg * 4) * HW + hw;
    float4 v0 = *(const float4*)&xb[0];
    float4 v1 = *(const float4*)&xb[HW];
    float4 v2 = *(const float4*)&xb[2 * HW];
    float4 v3 = *(const float4*)&xb[3 * HW];
    const float* vr[4] = {(const float*)&v0, (const float*)&v1,
                          (const float*)&v2, (const float*)&v3};
#pragma unroll
    for (int q = 0; q < 4; ++q) {
        usvec4 w;
        w[0] = f2bf(vr[0][q]);
        w[1] = f2bf(vr[1][q]);
        w[2] = f2bf(vr[2][q]);
        w[3] = f2bf(vr[3][q]);
        *(usvec4*)&T[(f * 4 + q) * 72 + cg * 4] = w;
    }
    __syncthreads();
#pragma unroll
    for (int it = 0; it < 2; ++it) {
        int idx  = it * 256 + t;
        int hw_l = idx >> 3, cgo = idx & 7;
        usvec8 w = *(const usvec8*)&T[hw_l * 72 + cgo * 8];
        *(usvec8*)&xt[(size_t)(n0 + hw_l) * CIN + c0 + cgo * 8] = w;
    }
}

// ---------------- shuffle+pad via LDS: y1sp[b][pos][c] from y1c[b][c][hw] ----------------
__global__ __launch_bounds__(256) void shuffle_pad_kernel(const unsigned short* __restrict__ y1c,
                                                          const int* __restrict__ permT,
                                                          unsigned short* __restrict__ y1sp) {
    __shared__ unsigned short Ly[32 * 800];   // 32 channels x plane, stride 800 (16B-aligned)
    const int b  = blockIdx.x >> 3;
    const int c0 = (blockIdx.x & 7) * 32;
    const int t = threadIdx.x;
#pragma unroll
    for (int it = 0; it < 13; ++it) {
        int chunk = it * 256 + t;
        if (chunk < 3136) {
            int c = chunk / 98, off8 = (chunk - c * 98) * 8;
            usvec8 v = *(const usvec8*)&y1c[((size_t)(b * P1 + c0 + c)) * HW + off8];
            *(usvec8*)&Ly[c * 800 + off8] = v;
        }
    }
    __syncthreads();
    const int pc = t & 31, pi = t >> 5;   // 32 channels x 8 positions
    unsigned short* yb = y1sp + (size_t)b * PADHW * P1 + c0 + pc;
#pragma unroll 4
    for (int it = 0; it < 98; ++it) {
        int p = it * 8 + pi;
        int pv = permT[p * P1 + c0 + pc];
        unsigned short val = Ly[pc * 800 + pv];
        int ph = p / WIMG, pw = p - ph * WIMG;
        yb[(size_t)((ph + 1) * PADW + pw + 1) * P1] = val;
    }
}

// ======================================================================
// GEMMs: 128x128 tile, 4 waves (2x2), BK=64 with XOR chunk swizzle,
// async global_load_lds (16B), double-buffered with counted vmcnt.
// ======================================================================

// ---------------- conv1: y1c[b][m][hw] = relu(W1 x X) ----------------
__global__ __launch_bounds__(256) void conv1_kernel(const unsigned short* __restrict__ xt,
                                                    const unsigned short* __restrict__ w1b,
                                                    unsigned short* __restrict__ y1c) {
    __shared__ __align__(16) unsigned short As[2 * 128 * 64];
    __shared__ __align__(16) unsigned short Bs[2 * 128 * 64];
    const int m0 = blockIdx.x * 128;
    const int n0 = blockIdx.y * 128;
    const int t = threadIdx.x;
    const int lane = t & 63, wave = t >> 6;
    const int l15 = lane & 15, quad = lane >> 4;
    const int wm = wave & 1, wn = wave >> 1;
    const int grow = lane >> 3;
    const int gsw  = ((lane & 7) ^ grow) << 3;     // swizzled k-chunk (ushort offset)
    const unsigned short* Asrc[4];
    const unsigned short* Bsrc[4];
    int ldso[4];
#pragma unroll
    for (int j = 0; j < 4; ++j) {
        int q = wave * 4 + j;
        int row = (q << 3) + grow;
        Asrc[j] = w1b + (size_t)(m0 + row) * CIN + gsw;
        Bsrc[j] = xt + (size_t)(n0 + row) * CIN + gsw;
        ldso[j] = q * 512;
    }
    const int coff0 = ((quad)     ^ (l15 & 7)) << 3;
    const int coff1 = ((quad + 4) ^ (l15 & 7)) << 3;

    accvec_t acc[4][4];
    const accvec_t zero = {0.f, 0.f, 0.f, 0.f};
#pragma unroll
    for (int i = 0; i < 4; ++i)
#pragma unroll
        for (int j = 0; j < 4; ++j) acc[i][j] = zero;

    auto stage = [&](int cur, int k0) {
        unsigned short* Ab = As + cur * 8192;
        unsigned short* Bb = Bs + cur * 8192;
#pragma unroll
        for (int j = 0; j < 4; ++j) {
            GLDS16(Asrc[j] + k0, Ab + ldso[j]);
            GLDS16(Bsrc[j] + k0, Bb + ldso[j]);
        }
    };
    auto compute = [&](int cur) {
        const unsigned short* Ab = As + cur * 8192;
        const unsigned short* Bb = Bs + cur * 8192;
        bfrag_t af[4], bfr[4];
#pragma unroll
        for (int i = 0; i < 4; ++i) {
            af[i]  = *(const bfrag_t*)&Ab[(wm * 64 + i * 16 + l15) * 64 + coff0];
            bfr[i] = *(const bfrag_t*)&Bb[(wn * 64 + i * 16 + l15) * 64 + coff0];
        }
#pragma unroll
        for (int im = 0; im < 4; ++im)
#pragma unroll
            for (int in = 0; in < 4; ++in)
                acc[im][in] = __builtin_amdgcn_mfma_f32_16x16x32_bf16(af[im], bfr[in], acc[im][in], 0, 0, 0);
#pragma unroll
        for (int i = 0; i < 4; ++i) {
            af[i]  = *(const bfrag_t*)&Ab[(wm * 64 + i * 16 + l15) * 64 + coff1];
            bfr[i] = *(const bfrag_t*)&Bb[(wn * 64 + i * 16 + l15) * 64 + coff1];
        }
#pragma unroll
        for (int im = 0; im < 4; ++im)
#pragma unroll
            for (int in = 0; in < 4; ++in)
                acc[im][in] = __builtin_amdgcn_mfma_f32_16x16x32_bf16(af[im], bfr[in], acc[im][in], 0, 0, 0);
    };

    stage(0, 0);                          // prologue: tile 0 -> buf 0
    for (int s = 0; s < 16; s += 2) {
        stage(1, (s + 1) << 6);
        WAITCNT_VM(8);
        RAW_BARRIER();
        compute(0);
        RAW_BARRIER();
        if (s + 2 < 16) { stage(0, (s + 2) << 6); WAITCNT_VM(8); }
        else            { WAITCNT_VM(0); }
        RAW_BARRIER();
        compute(1);
        RAW_BARRIER();
    }
    // coalesced store: y1c[b][m][hw], hw on l15
#pragma unroll
    for (int in = 0; in < 4; ++in) {
        const int n = n0 + wn * 64 + in * 16 + l15;
        const int b = n / HW, hw = n - b * HW;
#pragma unroll
        for (int im = 0; im < 4; ++im) {
#pragma unroll
            for (int r = 0; r < 4; ++r) {
                const int m = m0 + wm * 64 + im * 16 + (quad << 2) + r;
                float v = acc[im][in][r];
                v = v > 0.f ? v : 0.f;
                y1c[((size_t)(b * P1 + m)) * HW + hw] = f2bf(v);
            }
        }
    }
}

// ---------------- dconv: y2t[n][m] = relu(conv3x3(y1sp, wdb)) ----------------
// operands SWAPPED in mfma so D col(lane&15)=m -> m-contiguous stores
__global__ __launch_bounds__(256) void dconv_kernel(const unsigned short* __restrict__ y1sp,
                                                    const unsigned short* __restrict__ wdb,
                                                    unsigned short* __restrict__ y2t) {
    __shared__ __align__(16) unsigned short As[2 * 128 * 64];
    __shared__ __align__(16) unsigned short Bs[2 * 128 * 64];
    const int m0 = blockIdx.x * 128;
    const int n0 = blockIdx.y * 128;
    const int t = threadIdx.x;
    const int lane = t & 63, wave = t >> 6;
    const int l15 = lane & 15, quad = lane >> 4;
    const int wm = wave & 1, wn = wave >> 1;
    const int grow = lane >> 3;
    const int gsw  = ((lane & 7) ^ grow) << 3;
    const unsigned short* Asrc[4];
    const unsigned short* Bsrc[4];
    int ldso[4];
#pragma unroll
    for (int j = 0; j < 4; ++j) {
        int q = wave * 4 + j;
        int row = (q << 3) + grow;
        Asrc[j] = wdb + (size_t)(m0 + row) * P1 + gsw;
        int n = n0 + row;
        int b = n / HW, hw = n - b * HW;
        int h = hw / WIMG, w = hw - h * WIMG;
        Bsrc[j] = y1sp + ((size_t)b * PADHW + h * PADW + w) * P1 + gsw;  // top-left of 3x3 window
        ldso[j] = q * 512;
    }
    const int coff0 = ((quad)     ^ (l15 & 7)) << 3;
    const int coff1 = ((quad + 4) ^ (l15 & 7)) << 3;

    accvec_t acc[4][4];
    const accvec_t zero = {0.f, 0.f, 0.f, 0.f};
#pragma unroll
    for (int i = 0; i < 4; ++i)
#pragma unroll
        for (int j = 0; j < 4; ++j) acc[i][j] = zero;

    // 36 steps: s -> (tap r = s>>2, k0 = (s&3)*64)
    auto stage = [&](int cur, int s) {
        const int r  = s >> 2;
        const int k0 = (s & 3) << 6;
        const int kh = r / 3, kw = r - kh * 3;
        const size_t aoff = (size_t)r * (P1 * P2) + k0;
        const int    toff = (kh * PADW + kw) * P1 + k0;
        unsigned short* Ab = As + cur * 8192;
        unsigned short* Bb = Bs + cur * 8192;
#pragma unroll
        for (int j = 0; j < 4; ++j) {
            GLDS16(Asrc[j] + aoff, Ab + ldso[j]);
            GLDS16(Bsrc[j] + toff, Bb + ldso[j]);
        }
    };
    auto compute = [&](int cur) {
        const unsigned short* Ab = As + cur * 8192;
        const unsigned short* Bb = Bs + cur * 8192;
        bfrag_t af[4], bfr[4];
#pragma unroll
        for (int i = 0; i < 4; ++i) {
            af[i]  = *(const bfrag_t*)&Ab[(wm * 64 + i * 16 + l15) * 64 + coff0];
            bfr[i] = *(const bfrag_t*)&Bb[(wn * 64 + i * 16 + l15) * 64 + coff0];
        }
#pragma unroll
        for (int im = 0; im < 4; ++im)
#pragma unroll
            for (int in = 0; in < 4; ++in)
                acc[im][in] = __builtin_amdgcn_mfma_f32_16x16x32_bf16(bfr[in], af[im], acc[im][in], 0, 0, 0);
#pragma unroll
        for (int i = 0; i < 4; ++i) {
            af[i]  = *(const bfrag_t*)&Ab[(wm * 64 + i * 16 + l15) * 64 + coff1];
            bfr[i] = *(const bfrag_t*)&Bb[(wn * 64 + i * 16 + l15) * 64 + coff1];
        }
#pragma unroll
        for (int im = 0; im < 4; ++im)
#pragma unroll
            for (int in = 0; in < 4; ++in)
                acc[im][in] = __builtin_amdgcn_mfma_f32_16x16x32_bf16(bfr[in], af[im], acc[im][in], 0, 0, 0);
    };

    stage(0, 0);
    for (int s = 0; s < 36; s += 2) {
        stage(1, s + 1);                   // s+1 <= 35 always
        WAITCNT_VM(8);
        RAW_BARRIER();
        compute(0);
        RAW_BARRIER();
        if (s + 2 < 36) { stage(0, s + 2); WAITCNT_VM(8); }
        else            { WAITCNT_VM(0); }
        RAW_BARRIER();
        compute(1);
        RAW_BARRIER();
    }
    // swapped D mapping: col(l15)=m, row(quad*4+r)=n
#pragma unroll
    for (int im = 0; im < 4; ++im) {
        const int m = m0 + wm * 64 + im * 16 + l15;
#pragma unroll
        for (int in = 0; in < 4; ++in) {
#pragma unroll
            for (int r = 0; r < 4; ++r) {
                const int n = n0 + wn * 64 + in * 16 + (quad << 2) + r;
                float v = acc[im][in][r];
                v = v > 0.f ? v : 0.f;
                y2t[(size_t)n * P2 + m] = f2bf(v);
            }
        }
    }
}

// ---------------- conv3 + FUSED residual gather + relu ----------------
// Double-buffered K-loop + LDS-bounce epilogue. Residual is gathered
// directly from x (fp32) via perm_res in the epilogue: each thread loads
// 16 perm indices (2x int4, coalesced) and 16 scalar floats from the
// L3-hot (b,c) plane, prefetched one chunk ahead. Eliminates the
// res_shuffle kernel and its ~205 MB of intermediate traffic.
__global__ __launch_bounds__(256) void conv3_kernel(const unsigned short* __restrict__ y2t,
                                                    const unsigned short* __restrict__ w3b,
                                                    const float* __restrict__ x,
                                                    const int* __restrict__ perm_res,
                                                    float* __restrict__ out) {
    __shared__ __align__(16) unsigned short SMEM[16384];  // 32KB: As[2][4096] + Bs[2][4096]; Obuf aliases
    unsigned short* AsB = SMEM;           // buffers at +0 / +4096
    unsigned short* BsB = SMEM + 8192;    // buffers at +0 / +4096
    float* Obuf = (float*)SMEM;           // 32 rows x stride 132 floats (16.9KB)

    const int m0 = blockIdx.x * 128;
    const int n0 = blockIdx.y * 128;
    const int t = threadIdx.x;
    const int lane = t & 63, wave = t >> 6;
    const int l15 = lane & 15, quad = lane >> 4;
    const int wm = wave & 1, wn = wave >> 1;
    const int srow = lane >> 2, c8 = (lane & 3) << 3;
    const int row0 = wave * 32 + srow, row1 = row0 + 16;

    const unsigned short* a0 = w3b + (size_t)(m0 + row0) * P2 + c8;
    const unsigned short* a1 = w3b + (size_t)(m0 + row1) * P2 + c8;
    const unsigned short* b0 = y2t + (size_t)(n0 + row0) * P2 + c8;
    const unsigned short* b1 = y2t + (size_t)(n0 + row1) * P2 + c8;
    const int o0 = (wave * 2 + 0) * 512, o1 = (wave * 2 + 1) * 512;

    // epilogue geometry: thread t -> (erow = t>>3, eseg = t&7); a 16-n segment
    // never crosses a batch image (784 % 16 == 0, n0 % 128 == 0).
    const int erow = t >> 3, eseg = t & 7;
    const int n_e  = n0 + eseg * 16;
    const int b_e  = n_e / HW;
    const int hw_e = n_e - b_e * HW;
    const size_t ebase0 = ((size_t)(b_e * P3 + m0 + erow)) * HW + hw_e;

    // residual gather for chunk c: channel ch = m0 + c*32 + erow
    auto gather_res = [&](int c, float* rv) {
        const int ch = m0 + c * 32 + erow;
        const int* pr = perm_res + (size_t)ch * HW + hw_e;
        int4 pA = *(const int4*)&pr[0];
        int4 pB = *(const int4*)&pr[4];
        int4 pC = *(const int4*)&pr[8];
        int4 pD = *(const int4*)&pr[12];
        const float* xr = x + (size_t)(b_e * CIN + ch) * HW;
        rv[0]  = xr[pA.x]; rv[1]  = xr[pA.y]; rv[2]  = xr[pA.z]; rv[3]  = xr[pA.w];
        rv[4]  = xr[pB.x]; rv[5]  = xr[pB.y]; rv[6]  = xr[pB.z]; rv[7]  = xr[pB.w];
        rv[8]  = xr[pC.x]; rv[9]  = xr[pC.y]; rv[10] = xr[pC.z]; rv[11] = xr[pC.w];
        rv[12] = xr[pD.x]; rv[13] = xr[pD.y]; rv[14] = xr[pD.z]; rv[15] = xr[pD.w];
    };

    // prefetch chunk-0 residual
    float rsv[16];
    gather_res(0, rsv);

    accvec_t acc[4][4];
    const accvec_t zero = {0.f, 0.f, 0.f, 0.f};
#pragma unroll
    for (int i = 0; i < 4; ++i)
#pragma unroll
        for (int j = 0; j < 4; ++j) acc[i][j] = zero;

    auto stage = [&](int cur, int k0) {
        unsigned short* Ab = AsB + cur * 4096;
        unsigned short* Bb = BsB + cur * 4096;
        GLDS16(a0 + k0, Ab + o0);
        GLDS16(a1 + k0, Ab + o1);
        GLDS16(b0 + k0, Bb + o0);
        GLDS16(b1 + k0, Bb + o1);
    };
    auto compute = [&](int cur) {
        const unsigned short* Ab = AsB + cur * 4096;
        const unsigned short* Bb = BsB + cur * 4096;
        bfrag_t af[4], bfr[4];
#pragma unroll
        for (int i = 0; i < 4; ++i) {
            af[i]  = *(const bfrag_t*)&Ab[(wm * 64 + i * 16 + l15) * 32 + (quad << 3)];
            bfr[i] = *(const bfrag_t*)&Bb[(wn * 64 + i * 16 + l15) * 32 + (quad << 3)];
        }
#pragma unroll
        for (int im = 0; im < 4; ++im)
#pragma unroll
            for (int in = 0; in < 4; ++in)
                acc[im][in] = __builtin_amdgcn_mfma_f32_16x16x32_bf16(af[im], bfr[in], acc[im][in], 0, 0, 0);
    };

    stage(0, 0);
    for (int s = 0; s < 8; s += 2) {
        stage(1, (s + 1) << 5);
        WAITCNT_VM(4);
        RAW_BARRIER();
        compute(0);
        RAW_BARRIER();
        if (s + 2 < 8) { stage(0, (s + 2) << 5); WAITCNT_VM(4); }
        else           { WAITCNT_VM(0); }
        RAW_BARRIER();
        compute(1);
        RAW_BARRIER();
    }

    // ---- LDS-bounce epilogue: 4 chunks of 32 m-rows x 128 n ----
#pragma unroll
    for (int c = 0; c < 4; ++c) {
        if (wm == (c >> 1)) {
            const int imb = (c & 1) * 2;
#pragma unroll
            for (int i2 = 0; i2 < 2; ++i2)
#pragma unroll
                for (int in = 0; in < 4; ++in)
#pragma unroll
                    for (int r = 0; r < 4; ++r)
                        Obuf[(i2 * 16 + (quad << 2) + r) * 132 + wn * 64 + in * 16 + l15] =
                            acc[imb + i2][in][r];
        }
        __syncthreads();
        // prefetch next chunk's residual gather while this chunk drains
        float nxv[16];
#pragma unroll
        for (int j = 0; j < 16; ++j) nxv[j] = rsv[j];
        if (c < 3) gather_res(c + 1, nxv);
        {
            const size_t base = ebase0 + (size_t)c * 32 * HW;
            float ov[16];
#pragma unroll
            for (int q4 = 0; q4 < 4; ++q4) {
                float4 v = *(const float4*)&Obuf[erow * 132 + eseg * 16 + q4 * 4];
                ov[q4 * 4 + 0] = v.x; ov[q4 * 4 + 1] = v.y;
                ov[q4 * 4 + 2] = v.z; ov[q4 * 4 + 3] = v.w;
            }
#pragma unroll
            for (int q4 = 0; q4 < 4; ++q4) {
                float4 w;
                const int j = q4 * 4;
                float e0 = ov[j + 0] + rsv[j + 0];
                float e1 = ov[j + 1] + rsv[j + 1];
                float e2 = ov[j + 2] + rsv[j + 2];
                float e3 = ov[j + 3] + rsv[j + 3];
                w.x = e0 > 0.f ? e0 : 0.f;
                w.y = e1 > 0.f ? e1 : 0.f;
                w.z = e2 > 0.f ? e2 : 0.f;
                w.w = e3 > 0.f ? e3 : 0.f;
                *(float4*)&out[base + q4 * 4] = w;
            }
        }
#pragma unroll
        for (int j = 0; j < 16; ++j) rsv[j] = nxv[j];
        if (c < 3) __syncthreads();   // protect Obuf before next chunk's write phase
    }
}

extern "C" void kernel_launch(void* const* d_in, const int* in_sizes, int n_in,
                              void* d_out, int out_size, void* d_ws, size_t ws_size,
                              hipStream_t stream) {
    const float* x      = (const float*)d_in[0];
    const float* w1     = (const float*)d_in[1];
    const float* wd     = (const float*)d_in[2];
    const float* w3     = (const float*)d_in[3];
    const int*   perm_d = (const int*)d_in[4];
    const int*   perm_r = (const int*)d_in[5];
    float*       out    = (float*)d_out;

    char* ws = (char*)d_ws;
    unsigned short* y1sp  = (unsigned short*)(ws + 0);         // 14,745,600
    unsigned short* y2t   = (unsigned short*)(ws + 14745600);  // 12,845,056 (also y1c — dconv overwrites after shuffle_pad consumed it)
    int*            permT = (int*)(ws + 27590656);             //    802,816
    unsigned short* w1b   = (unsigned short*)(ws + 28393472);  //    524,288
    unsigned short* wdb   = (unsigned short*)(ws + 28917760);  //  1,179,648
    unsigned short* w3b   = (unsigned short*)(ws + 30097408);  //    524,288
    unsigned short* xt    = (unsigned short*)(ws + 30621696);  // 51,380,224
    unsigned short* y1c   = y2t;

    hipMemsetAsync(y1sp, 0, (size_t)BATCH * PADHW * P1 * sizeof(unsigned short), stream);
    permT_kernel<<<dim3(HW), dim3(256), 0, stream>>>(perm_d, permT);
    pack_weights_kernel<<<dim3(4352), dim3(256), 0, stream>>>(w1, wd, w3, w1b, wdb, w3b);
    transpose_x_kernel<<<dim3(CIN / 64, NFLAT / 64), dim3(256), 0, stream>>>(x, xt);

    conv1_kernel<<<dim3(P1 / 128, NFLAT / 128), dim3(256), 0, stream>>>(xt, w1b, y1c);
    shuffle_pad_kernel<<<dim3(BATCH * 8), dim3(256), 0, stream>>>(y1c, permT, y1sp);
    dconv_kernel<<<dim3(P2 / 128, NFLAT / 128), dim3(256), 0, stream>>>(y1sp, wdb, y2t);
    conv3_kernel<<<dim3(P3 / 128, NFLAT / 128), dim3(256), 0, stream>>>(y2t, w3b, x, perm_r, out);
}

// Round 5
// 351.146 us; speedup vs baseline: 1.0519x; 1.0519x over previous
//
#include <hip/hip_runtime.h>
#include <hip/hip_bf16.h>

// Problem constants
#define BATCH 32
#define CIN   1024
#define HW    784     // 28*28
#define WIMG  28
#define PADW  30      // padded 30x30 plane
#define PADHW 900
#define P1    256
#define P2    256
#define P3    1024
#define NFLAT (BATCH * HW)   // 25088 = 196 * 128 = 392 * 64 exactly

typedef __attribute__((ext_vector_type(8))) short bfrag_t;          // 8 bf16 (4 VGPRs)
typedef __attribute__((ext_vector_type(8))) unsigned short usvec8;
typedef __attribute__((ext_vector_type(4))) unsigned short usvec4;
typedef __attribute__((ext_vector_type(4))) float accvec_t;

static __device__ __forceinline__ unsigned short f2bf(float f) {
    union { __hip_bfloat16 h; unsigned short u; } cv;
    cv.h = __float2bfloat16(f);
    return cv.u;
}
static __device__ __forceinline__ float bf2f(unsigned short u) {
    union { float f; unsigned int i; } cv;
    cv.i = ((unsigned int)u) << 16;
    return cv.f;
}

// async 16B global->LDS DMA. LDS dest is wave-uniform base + lane*16B.
#define GLDS16(g, l) __builtin_amdgcn_global_load_lds(                      \
        (const __attribute__((address_space(1))) void*)(g),                 \
        (__attribute__((address_space(3))) void*)(l), 16, 0, 0)

// barrier WITHOUT compiler-inserted vmcnt(0) drain; pinned against code motion
#define RAW_BARRIER() do {                         \
        __builtin_amdgcn_sched_barrier(0);         \
        __builtin_amdgcn_s_barrier();              \
        __builtin_amdgcn_sched_barrier(0);         \
    } while (0)
#define WAITCNT_VM(N) do {                                        \
        asm volatile("s_waitcnt vmcnt(" #N ")" ::: "memory");     \
        __builtin_amdgcn_sched_barrier(0);                        \
    } while (0)

// ---------------- pre-pass: transpose perm_dconv -> permT[p][c] ----------------
__global__ __launch_bounds__(256) void permT_kernel(const int* __restrict__ perm,
                                                    int* __restrict__ permT) {
    int p = blockIdx.x, c = threadIdx.x;
    permT[p * P1 + c] = perm[c * HW + p];
}

// ---------------- pre-pass: pack weights to bf16 ----------------
// w1b[m][k]; w3b[m][k]; wdb[r][m][k] = bf16(wd[m][k][r])
__global__ __launch_bounds__(256) void pack_weights_kernel(
        const float* __restrict__ w1, const float* __restrict__ wd,
        const float* __restrict__ w3, unsigned short* __restrict__ w1b,
        unsigned short* __restrict__ wdb, unsigned short* __restrict__ w3b) {
    int i = blockIdx.x * 256 + threadIdx.x;
    if (i < 262144) w1b[i] = f2bf(w1[i]);
    int i2 = i - 262144;
    if (i2 >= 0 && i2 < 262144) w3b[i2] = f2bf(w3[i2]);
    int i3 = i - 524288;
    if (i3 >= 0 && i3 < 589824) {
        int m = i3 / 2304, rem = i3 - m * 2304;
        int k = rem / 9, r = rem - k * 9;
        wdb[((size_t)r * P2 + m) * P1 + k] = f2bf(wd[i3]);
    }
}

// ---------------- pre-pass: transpose x -> xt[n][c] bf16, n = b*HW+hw ----------------
__global__ __launch_bounds__(256) void transpose_x_kernel(const float* __restrict__ x,
                                                          unsigned short* __restrict__ xt) {
    __shared__ __align__(16) unsigned short T[64 * 72];   // [hw_local][c_local], stride 72
    const int c0 = blockIdx.x * 64;
    const int n0 = blockIdx.y * 64;
    const int t  = threadIdx.x;
    const int f  = t & 15;          // hw-quad index: hw_local = 4f..4f+3
    const int cg = t >> 4;          // channel group: c_local = 4cg..4cg+3
    const int n  = n0 + f * 4;
    const int b  = n / HW, hw = n - b * HW;       // float4 never straddles b (784 % 4 == 0)
    const float* xb = x + ((size_t)b * CIN + c0 + cg * 4) * HW + hw;
    float4 v0 = *(const float4*)&xb[0];
    float4 v1 = *(const float4*)&xb[HW];
    float4 v2 = *(const float4*)&xb[2 * HW];
    float4 v3 = *(const float4*)&xb[3 * HW];
    const float* vr[4] = {(const float*)&v0, (const float*)&v1,
                          (const float*)&v2, (const float*)&v3};
#pragma unroll
    for (int q = 0; q < 4; ++q) {
        usvec4 w;
        w[0] = f2bf(vr[0][q]);
        w[1] = f2bf(vr[1][q]);
        w[2] = f2bf(vr[2][q]);
        w[3] = f2bf(vr[3][q]);
        *(usvec4*)&T[(f * 4 + q) * 72 + cg * 4] = w;
    }
    __syncthreads();
#pragma unroll
    for (int it = 0; it < 2; ++it) {
        int idx  = it * 256 + t;
        int hw_l = idx >> 3, cgo = idx & 7;
        usvec8 w = *(const usvec8*)&T[hw_l * 72 + cgo * 8];
        *(usvec8*)&xt[(size_t)(n0 + hw_l) * CIN + c0 + cgo * 8] = w;
    }
}

// ---------------- residual shuffle via LDS: res[b][c][hw] = bf16(x[b][c][perm_res[c][hw]]) ----
__global__ __launch_bounds__(256) void res_shuffle_kernel(const float* __restrict__ x,
                                                          const int* __restrict__ perm_res,
                                                          unsigned short* __restrict__ res) {
    __shared__ float Lx[8 * 788];     // 8 rows, stride 788 (16B-aligned)
    const int g0 = blockIdx.x * 8;    // 8 (b,c) rows per block
    const int t = threadIdx.x;
#pragma unroll
    for (int it = 0; it < 7; ++it) {
        int chunk = it * 256 + t;
        if (chunk < 1568) {
            int r = chunk / 196, off = (chunk - r * 196) * 4;
            float4 v = *(const float4*)&x[(size_t)(g0 + r) * HW + off];
            *(float4*)&Lx[r * 788 + off] = v;
        }
    }
    __syncthreads();
    const int q0 = t & 63;
#pragma unroll
    for (int rp = 0; rp < 2; ++rp) {
        int r = rp * 4 + (t >> 6);
        int g = g0 + r;
        int m = g & (CIN - 1);
        const int* pr = perm_res + (size_t)m * HW;
#pragma unroll
        for (int it = 0; it < 13; ++it) {
            int q = it * 64 + q0;
            if (q < HW) {
                int pv = pr[q];
                res[(size_t)g * HW + q] = f2bf(Lx[r * 788 + pv]);
            }
        }
    }
}

// ---------------- shuffle+pad via LDS: y1sp[b][pos][c] from y1c[b][c][hw] ----------------
// 512 threads (was 256): halves the serial 98-iter gather loop; grid is only
// 256 blocks (1/CU) so extra waves directly raise occupancy / latency hiding.
__global__ __launch_bounds__(512) void shuffle_pad_kernel(const unsigned short* __restrict__ y1c,
                                                          const int* __restrict__ permT,
                                                          unsigned short* __restrict__ y1sp) {
    __shared__ unsigned short Ly[32 * 800];   // 32 channels x plane, stride 800 (16B-aligned)
    const int b  = blockIdx.x >> 3;
    const int c0 = (blockIdx.x & 7) * 32;
    const int t = threadIdx.x;
    // phase 1: coalesced 16B loads of 32 channel rows (3136 chunks of 8 ushorts)
#pragma unroll
    for (int it = 0; it < 7; ++it) {
        int chunk = it * 512 + t;
        if (chunk < 3136) {
            int c = chunk / 98, off8 = (chunk - c * 98) * 8;
            usvec8 v = *(const usvec8*)&y1c[((size_t)(b * P1 + c0 + c)) * HW + off8];
            *(usvec8*)&Ly[c * 800 + off8] = v;
        }
    }
    __syncthreads();
    // phase 2: per output pos, gather per-channel source, write 64B channel segments
    const int pc = t & 31, pi = t >> 5;   // 32 channels x 16 positions
    unsigned short* yb = y1sp + (size_t)b * PADHW * P1 + c0 + pc;
#pragma unroll 7
    for (int it = 0; it < 49; ++it) {
        int p = it * 16 + pi;
        int pv = permT[p * P1 + c0 + pc];
        unsigned short val = Ly[pc * 800 + pv];
        int ph = p / WIMG, pw = p - ph * WIMG;
        yb[(size_t)((ph + 1) * PADW + pw + 1) * P1] = val;
    }
}

// ======================================================================
// GEMMs: 128x128 tile, 4 waves (2x2), BK=64 with XOR chunk swizzle,
// async global_load_lds (16B), double-buffered with counted vmcnt.
// ======================================================================

// ---------------- conv1: y1c[b][m][hw] = relu(W1 x X) ----------------
__global__ __launch_bounds__(256) void conv1_kernel(const unsigned short* __restrict__ xt,
                                                    const unsigned short* __restrict__ w1b,
                                                    unsigned short* __restrict__ y1c) {
    __shared__ __align__(16) unsigned short As[2 * 128 * 64];
    __shared__ __align__(16) unsigned short Bs[2 * 128 * 64];
    const int m0 = blockIdx.x * 128;
    const int n0 = blockIdx.y * 128;
    const int t = threadIdx.x;
    const int lane = t & 63, wave = t >> 6;
    const int l15 = lane & 15, quad = lane >> 4;
    const int wm = wave & 1, wn = wave >> 1;
    const int grow = lane >> 3;
    const int gsw  = ((lane & 7) ^ grow) << 3;     // swizzled k-chunk (ushort offset)
    const unsigned short* Asrc[4];
    const unsigned short* Bsrc[4];
    int ldso[4];
#pragma unroll
    for (int j = 0; j < 4; ++j) {
        int q = wave * 4 + j;
        int row = (q << 3) + grow;
        Asrc[j] = w1b + (size_t)(m0 + row) * CIN + gsw;
        Bsrc[j] = xt + (size_t)(n0 + row) * CIN + gsw;
        ldso[j] = q * 512;
    }
    const int coff0 = ((quad)     ^ (l15 & 7)) << 3;
    const int coff1 = ((quad + 4) ^ (l15 & 7)) << 3;

    accvec_t acc[4][4];
    const accvec_t zero = {0.f, 0.f, 0.f, 0.f};
#pragma unroll
    for (int i = 0; i < 4; ++i)
#pragma unroll
        for (int j = 0; j < 4; ++j) acc[i][j] = zero;

    auto stage = [&](int cur, int k0) {
        unsigned short* Ab = As + cur * 8192;
        unsigned short* Bb = Bs + cur * 8192;
#pragma unroll
        for (int j = 0; j < 4; ++j) {
            GLDS16(Asrc[j] + k0, Ab + ldso[j]);
            GLDS16(Bsrc[j] + k0, Bb + ldso[j]);
        }
    };
    auto compute = [&](int cur) {
        const unsigned short* Ab = As + cur * 8192;
        const unsigned short* Bb = Bs + cur * 8192;
        bfrag_t af[4], bfr[4];
#pragma unroll
        for (int i = 0; i < 4; ++i) {
            af[i]  = *(const bfrag_t*)&Ab[(wm * 64 + i * 16 + l15) * 64 + coff0];
            bfr[i] = *(const bfrag_t*)&Bb[(wn * 64 + i * 16 + l15) * 64 + coff0];
        }
#pragma unroll
        for (int im = 0; im < 4; ++im)
#pragma unroll
            for (int in = 0; in < 4; ++in)
                acc[im][in] = __builtin_amdgcn_mfma_f32_16x16x32_bf16(af[im], bfr[in], acc[im][in], 0, 0, 0);
#pragma unroll
        for (int i = 0; i < 4; ++i) {
            af[i]  = *(const bfrag_t*)&Ab[(wm * 64 + i * 16 + l15) * 64 + coff1];
            bfr[i] = *(const bfrag_t*)&Bb[(wn * 64 + i * 16 + l15) * 64 + coff1];
        }
#pragma unroll
        for (int im = 0; im < 4; ++im)
#pragma unroll
            for (int in = 0; in < 4; ++in)
                acc[im][in] = __builtin_amdgcn_mfma_f32_16x16x32_bf16(af[im], bfr[in], acc[im][in], 0, 0, 0);
    };

    stage(0, 0);                          // prologue: tile 0 -> buf 0
    for (int s = 0; s < 16; s += 2) {
        stage(1, (s + 1) << 6);
        WAITCNT_VM(8);
        RAW_BARRIER();
        compute(0);
        RAW_BARRIER();
        if (s + 2 < 16) { stage(0, (s + 2) << 6); WAITCNT_VM(8); }
        else            { WAITCNT_VM(0); }
        RAW_BARRIER();
        compute(1);
        RAW_BARRIER();
    }
    // coalesced store: y1c[b][m][hw], hw on l15
#pragma unroll
    for (int in = 0; in < 4; ++in) {
        const int n = n0 + wn * 64 + in * 16 + l15;
        const int b = n / HW, hw = n - b * HW;
#pragma unroll
        for (int im = 0; im < 4; ++im) {
#pragma unroll
            for (int r = 0; r < 4; ++r) {
                const int m = m0 + wm * 64 + im * 16 + (quad << 2) + r;
                float v = acc[im][in][r];
                v = v > 0.f ? v : 0.f;
                y1c[((size_t)(b * P1 + m)) * HW + hw] = f2bf(v);
            }
        }
    }
}

// ---------------- dconv: y2t[n][m] = relu(conv3x3(y1sp, wdb)) ----------------
// operands SWAPPED in mfma so D col(lane&15)=m -> m-contiguous stores
__global__ __launch_bounds__(256) void dconv_kernel(const unsigned short* __restrict__ y1sp,
                                                    const unsigned short* __restrict__ wdb,
                                                    unsigned short* __restrict__ y2t) {
    __shared__ __align__(16) unsigned short As[2 * 128 * 64];
    __shared__ __align__(16) unsigned short Bs[2 * 128 * 64];
    const int m0 = blockIdx.x * 128;
    const int n0 = blockIdx.y * 128;
    const int t = threadIdx.x;
    const int lane = t & 63, wave = t >> 6;
    const int l15 = lane & 15, quad = lane >> 4;
    const int wm = wave & 1, wn = wave >> 1;
    const int grow = lane >> 3;
    const int gsw  = ((lane & 7) ^ grow) << 3;
    const unsigned short* Asrc[4];
    const unsigned short* Bsrc[4];
    int ldso[4];
#pragma unroll
    for (int j = 0; j < 4; ++j) {
        int q = wave * 4 + j;
        int row = (q << 3) + grow;
        Asrc[j] = wdb + (size_t)(m0 + row) * P1 + gsw;
        int n = n0 + row;
        int b = n / HW, hw = n - b * HW;
        int h = hw / WIMG, w = hw - h * WIMG;
        Bsrc[j] = y1sp + ((size_t)b * PADHW + h * PADW + w) * P1 + gsw;  // top-left of 3x3 window
        ldso[j] = q * 512;
    }
    const int coff0 = ((quad)     ^ (l15 & 7)) << 3;
    const int coff1 = ((quad + 4) ^ (l15 & 7)) << 3;

    accvec_t acc[4][4];
    const accvec_t zero = {0.f, 0.f, 0.f, 0.f};
#pragma unroll
    for (int i = 0; i < 4; ++i)
#pragma unroll
        for (int j = 0; j < 4; ++j) acc[i][j] = zero;

    // 36 steps: s -> (tap r = s>>2, k0 = (s&3)*64)
    auto stage = [&](int cur, int s) {
        const int r  = s >> 2;
        const int k0 = (s & 3) << 6;
        const int kh = r / 3, kw = r - kh * 3;
        const size_t aoff = (size_t)r * (P1 * P2) + k0;
        const int    toff = (kh * PADW + kw) * P1 + k0;
        unsigned short* Ab = As + cur * 8192;
        unsigned short* Bb = Bs + cur * 8192;
#pragma unroll
        for (int j = 0; j < 4; ++j) {
            GLDS16(Asrc[j] + aoff, Ab + ldso[j]);
            GLDS16(Bsrc[j] + toff, Bb + ldso[j]);
        }
    };
    auto compute = [&](int cur) {
        const unsigned short* Ab = As + cur * 8192;
        const unsigned short* Bb = Bs + cur * 8192;
        bfrag_t af[4], bfr[4];
#pragma unroll
        for (int i = 0; i < 4; ++i) {
            af[i]  = *(const bfrag_t*)&Ab[(wm * 64 + i * 16 + l15) * 64 + coff0];
            bfr[i] = *(const bfrag_t*)&Bb[(wn * 64 + i * 16 + l15) * 64 + coff0];
        }
#pragma unroll
        for (int im = 0; im < 4; ++im)
#pragma unroll
            for (int in = 0; in < 4; ++in)
                acc[im][in] = __builtin_amdgcn_mfma_f32_16x16x32_bf16(bfr[in], af[im], acc[im][in], 0, 0, 0);
#pragma unroll
        for (int i = 0; i < 4; ++i) {
            af[i]  = *(const bfrag_t*)&Ab[(wm * 64 + i * 16 + l15) * 64 + coff1];
            bfr[i] = *(const bfrag_t*)&Bb[(wn * 64 + i * 16 + l15) * 64 + coff1];
        }
#pragma unroll
        for (int im = 0; im < 4; ++im)
#pragma unroll
            for (int in = 0; in < 4; ++in)
                acc[im][in] = __builtin_amdgcn_mfma_f32_16x16x32_bf16(bfr[in], af[im], acc[im][in], 0, 0, 0);
    };

    stage(0, 0);
    for (int s = 0; s < 36; s += 2) {
        stage(1, s + 1);                   // s+1 <= 35 always
        WAITCNT_VM(8);
        RAW_BARRIER();
        compute(0);
        RAW_BARRIER();
        if (s + 2 < 36) { stage(0, s + 2); WAITCNT_VM(8); }
        else            { WAITCNT_VM(0); }
        RAW_BARRIER();
        compute(1);
        RAW_BARRIER();
    }
    // swapped D mapping: col(l15)=m, row(quad*4+r)=n
#pragma unroll
    for (int im = 0; im < 4; ++im) {
        const int m = m0 + wm * 64 + im * 16 + l15;
#pragma unroll
        for (int in = 0; in < 4; ++in) {
#pragma unroll
            for (int r = 0; r < 4; ++r) {
                const int n = n0 + wn * 64 + in * 16 + (quad << 2) + r;
                float v = acc[im][in][r];
                v = v > 0.f ? v : 0.f;
                y2t[(size_t)n * P2 + m] = f2bf(v);
            }
        }
    }
}

// ---------------- conv3 + residual add + relu ----------------
// Double-buffered K-loop (BK=32, 8 steps) + LDS-bounce epilogue with staged
// bf16 residual (REVERTED from R3's in-kernel gather: scalar gathers amplify
// L2 traffic 16x — gathers must go through LDS, i.e. res_shuffle).
__global__ __launch_bounds__(256) void conv3_kernel(const unsigned short* __restrict__ y2t,
                                                    const unsigned short* __restrict__ w3b,
                                                    const unsigned short* __restrict__ res,
                                                    float* __restrict__ out) {
    __shared__ __align__(16) unsigned short SMEM[16384];  // 32KB: As[2][4096] + Bs[2][4096]; Obuf aliases
    unsigned short* AsB = SMEM;           // buffers at +0 / +4096
    unsigned short* BsB = SMEM + 8192;    // buffers at +0 / +4096
    float* Obuf = (float*)SMEM;           // 32 rows x stride 132 floats (16.9KB)

    const int m0 = blockIdx.x * 128;
    const int n0 = blockIdx.y * 128;
    const int t = threadIdx.x;
    const int lane = t & 63, wave = t >> 6;
    const int l15 = lane & 15, quad = lane >> 4;
    const int wm = wave & 1, wn = wave >> 1;
    const int srow = lane >> 2, c8 = (lane & 3) << 3;
    const int row0 = wave * 32 + srow, row1 = row0 + 16;

    const unsigned short* a0 = w3b + (size_t)(m0 + row0) * P2 + c8;
    const unsigned short* a1 = w3b + (size_t)(m0 + row1) * P2 + c8;
    const unsigned short* b0 = y2t + (size_t)(n0 + row0) * P2 + c8;
    const unsigned short* b1 = y2t + (size_t)(n0 + row1) * P2 + c8;
    const int o0 = (wave * 2 + 0) * 512, o1 = (wave * 2 + 1) * 512;

    // epilogue geometry: thread t -> (erow = t>>3, eseg = t&7); a 16-n segment
    // never crosses a batch image (784 % 16 == 0, n0 % 128 == 0).
    const int erow = t >> 3, eseg = t & 7;
    const int n_e  = n0 + eseg * 16;
    const int b_e  = n_e / HW;
    const int hw_e = n_e - b_e * HW;
    const size_t ebase0 = ((size_t)(b_e * P3 + m0 + erow)) * HW + hw_e;

    // prefetch chunk-0 residual (16 bf16 = 2 x 16B, 32B-aligned)
    usvec8 rsA = *(const usvec8*)&res[ebase0];
    usvec8 rsB = *(const usvec8*)&res[ebase0 + 8];

    accvec_t acc[4][4];
    const accvec_t zero = {0.f, 0.f, 0.f, 0.f};
#pragma unroll
    for (int i = 0; i < 4; ++i)
#pragma unroll
        for (int j = 0; j < 4; ++j) acc[i][j] = zero;

    auto stage = [&](int cur, int k0) {
        unsigned short* Ab = AsB + cur * 4096;
        unsigned short* Bb = BsB + cur * 4096;
        GLDS16(a0 + k0, Ab + o0);
        GLDS16(a1 + k0, Ab + o1);
        GLDS16(b0 + k0, Bb + o0);
        GLDS16(b1 + k0, Bb + o1);
    };
    auto compute = [&](int cur) {
        const unsigned short* Ab = AsB + cur * 4096;
        const unsigned short* Bb = BsB + cur * 4096;
        bfrag_t af[4], bfr[4];
#pragma unroll
        for (int i = 0; i < 4; ++i) {
            af[i]  = *(const bfrag_t*)&Ab[(wm * 64 + i * 16 + l15) * 32 + (quad << 3)];
            bfr[i] = *(const bfrag_t*)&Bb[(wn * 64 + i * 16 + l15) * 32 + (quad << 3)];
        }
#pragma unroll
        for (int im = 0; im < 4; ++im)
#pragma unroll
            for (int in = 0; in < 4; ++in)
                acc[im][in] = __builtin_amdgcn_mfma_f32_16x16x32_bf16(af[im], bfr[in], acc[im][in], 0, 0, 0);
    };

    stage(0, 0);
    for (int s = 0; s < 8; s += 2) {
        stage(1, (s + 1) << 5);
        WAITCNT_VM(4);
        RAW_BARRIER();
        compute(0);
        RAW_BARRIER();
        if (s + 2 < 8) { stage(0, (s + 2) << 5); WAITCNT_VM(4); }
        else           { WAITCNT_VM(0); }
        RAW_BARRIER();
        compute(1);
        RAW_BARRIER();
    }

    // ---- LDS-bounce epilogue: 4 chunks of 32 m-rows x 128 n ----
#pragma unroll
    for (int c = 0; c < 4; ++c) {
        if (wm == (c >> 1)) {
            const int imb = (c & 1) * 2;
#pragma unroll
            for (int i2 = 0; i2 < 2; ++i2)
#pragma unroll
                for (int in = 0; in < 4; ++in)
#pragma unroll
                    for (int r = 0; r < 4; ++r)
                        Obuf[(i2 * 16 + (quad << 2) + r) * 132 + wn * 64 + in * 16 + l15] =
                            acc[imb + i2][in][r];
        }
        __syncthreads();
        usvec8 nxA = rsA, nxB = rsB;
        if (c < 3) {
            const size_t nb = ebase0 + (size_t)(c + 1) * 32 * HW;
            nxA = *(const usvec8*)&res[nb];
            nxB = *(const usvec8*)&res[nb + 8];
        }
        {
            const size_t base = ebase0 + (size_t)c * 32 * HW;
            float ov[16];
#pragma unroll
            for (int q4 = 0; q4 < 4; ++q4) {
                float4 v = *(const float4*)&Obuf[erow * 132 + eseg * 16 + q4 * 4];
                ov[q4 * 4 + 0] = v.x; ov[q4 * 4 + 1] = v.y;
                ov[q4 * 4 + 2] = v.z; ov[q4 * 4 + 3] = v.w;
            }
#pragma unroll
            for (int q4 = 0; q4 < 4; ++q4) {
                float4 w;
                float e0, e1, e2, e3;
                const int j = q4 * 4;
                e0 = ov[j + 0] + bf2f((unsigned short)(j + 0 < 8 ? rsA[j + 0] : rsB[j + 0 - 8]));
                e1 = ov[j + 1] + bf2f((unsigned short)(j + 1 < 8 ? rsA[j + 1] : rsB[j + 1 - 8]));
                e2 = ov[j + 2] + bf2f((unsigned short)(j + 2 < 8 ? rsA[j + 2] : rsB[j + 2 - 8]));
                e3 = ov[j + 3] + bf2f((unsigned short)(j + 3 < 8 ? rsA[j + 3] : rsB[j + 3 - 8]));
                w.x = e0 > 0.f ? e0 : 0.f;
                w.y = e1 > 0.f ? e1 : 0.f;
                w.z = e2 > 0.f ? e2 : 0.f;
                w.w = e3 > 0.f ? e3 : 0.f;
                *(float4*)&out[base + q4 * 4] = w;
            }
        }
        rsA = nxA; rsB = nxB;
        if (c < 3) __syncthreads();   // protect Obuf before next chunk's write phase
    }
}

extern "C" void kernel_launch(void* const* d_in, const int* in_sizes, int n_in,
                              void* d_out, int out_size, void* d_ws, size_t ws_size,
                              hipStream_t stream) {
    const float* x      = (const float*)d_in[0];
    const float* w1     = (const float*)d_in[1];
    const float* wd     = (const float*)d_in[2];
    const float* w3     = (const float*)d_in[3];
    const int*   perm_d = (const int*)d_in[4];
    const int*   perm_r = (const int*)d_in[5];
    float*       out    = (float*)d_out;

    char* ws = (char*)d_ws;
    unsigned short* y1sp  = (unsigned short*)(ws + 0);         // 14,745,600
    unsigned short* y2t   = (unsigned short*)(ws + 14745600);  // 12,845,056 (also y1c — dconv overwrites after shuffle_pad consumed it)
    int*            permT = (int*)(ws + 27590656);             //    802,816
    unsigned short* w1b   = (unsigned short*)(ws + 28393472);  //    524,288
    unsigned short* wdb   = (unsigned short*)(ws + 28917760);  //  1,179,648
    unsigned short* w3b   = (unsigned short*)(ws + 30097408);  //    524,288
    unsigned short* xt    = (unsigned short*)(ws + 30621696);  // 51,380,224 (also res — res_shuffle overwrites after conv1 consumed it)
    unsigned short* resb  = xt;
    unsigned short* y1c   = y2t;

    hipMemsetAsync(y1sp, 0, (size_t)BATCH * PADHW * P1 * sizeof(unsigned short), stream);
    permT_kernel<<<dim3(HW), dim3(256), 0, stream>>>(perm_d, permT);
    pack_weights_kernel<<<dim3(4352), dim3(256), 0, stream>>>(w1, wd, w3, w1b, wdb, w3b);
    transpose_x_kernel<<<dim3(CIN / 64, NFLAT / 64), dim3(256), 0, stream>>>(x, xt);

    conv1_kernel<<<dim3(P1 / 128, NFLAT / 128), dim3(256), 0, stream>>>(xt, w1b, y1c);
    res_shuffle_kernel<<<dim3(BATCH * CIN / 8), dim3(256), 0, stream>>>(x, perm_r, resb);
    shuffle_pad_kernel<<<dim3(BATCH * 8), dim3(512), 0, stream>>>(y1c, permT, y1sp);
    dconv_kernel<<<dim3(P2 / 128, NFLAT / 128), dim3(256), 0, stream>>>(y1sp, wdb, y2t);
    conv3_kernel<<<dim3(P3 / 128, NFLAT / 128), dim3(256), 0, stream>>>(y2t, w3b, resb, out);
}

// Round 6
// 331.506 us; speedup vs baseline: 1.1143x; 1.0592x over previous
//
#include <hip/hip_runtime.h>
#include <hip/hip_bf16.h>

// Problem constants
#define BATCH 32
#define CIN   1024
#define HW    784     // 28*28
#define WIMG  28
#define PADW  30      // padded 30x30 plane
#define PADHW 900
#define P1    256
#define P2    256
#define P3    1024
#define NFLAT (BATCH * HW)   // 25088 = 196 * 128 = 392 * 64 exactly

typedef __attribute__((ext_vector_type(8))) short bfrag_t;          // 8 bf16 (4 VGPRs)
typedef __attribute__((ext_vector_type(8))) unsigned short usvec8;
typedef __attribute__((ext_vector_type(4))) unsigned short usvec4;
typedef __attribute__((ext_vector_type(4))) float accvec_t;

static __device__ __forceinline__ unsigned short f2bf(float f) {
    union { __hip_bfloat16 h; unsigned short u; } cv;
    cv.h = __float2bfloat16(f);
    return cv.u;
}
static __device__ __forceinline__ float bf2f(unsigned short u) {
    union { float f; unsigned int i; } cv;
    cv.i = ((unsigned int)u) << 16;
    return cv.f;
}

// async 16B global->LDS DMA. LDS dest is wave-uniform base + lane*16B.
#define GLDS16(g, l) __builtin_amdgcn_global_load_lds(                      \
        (const __attribute__((address_space(1))) void*)(g),                 \
        (__attribute__((address_space(3))) void*)(l), 16, 0, 0)

// barrier WITHOUT compiler-inserted vmcnt(0) drain; pinned against code motion
#define RAW_BARRIER() do {                         \
        __builtin_amdgcn_sched_barrier(0);         \
        __builtin_amdgcn_s_barrier();              \
        __builtin_amdgcn_sched_barrier(0);         \
    } while (0)
#define WAITCNT_VM(N) do {                                        \
        asm volatile("s_waitcnt vmcnt(" #N ")" ::: "memory");     \
        __builtin_amdgcn_sched_barrier(0);                        \
    } while (0)

// ======================================================================
// PREP (fused): [0,6272) transpose_x | [6272,10624) pack_weights |
// [10624,11408) permT | [11408,15008) y1sp zero-fill. All branches are
// mutually independent (read external inputs, write disjoint ws buffers).
// ======================================================================
__global__ __launch_bounds__(256) void prep_kernel(
        const float* __restrict__ x, unsigned short* __restrict__ xt,
        const float* __restrict__ w1, const float* __restrict__ wd,
        const float* __restrict__ w3, unsigned short* __restrict__ w1b,
        unsigned short* __restrict__ wdb, unsigned short* __restrict__ w3b,
        const int* __restrict__ perm, int* __restrict__ permT,
        unsigned short* __restrict__ y1sp) {
    __shared__ __align__(16) unsigned short T[64 * 72];   // transpose branch only
    const int bid = blockIdx.x;
    const int t   = threadIdx.x;
    if (bid < 6272) {
        // ---- transpose x -> xt[n][c] bf16 (NFLAT=392*64, no guards) ----
        const int c0 = (bid & 15) * 64;
        const int n0 = (bid >> 4) * 64;
        const int f  = t & 15;          // hw-quad: hw_local = 4f..4f+3
        const int cg = t >> 4;          // channel group: c_local = 4cg..4cg+3
        const int n  = n0 + f * 4;
        const int b  = n / HW, hw = n - b * HW;   // float4 never straddles b
        const float* xb = x + ((size_t)b * CIN + c0 + cg * 4) * HW + hw;
        float4 v0 = *(const float4*)&xb[0];
        float4 v1 = *(const float4*)&xb[HW];
        float4 v2 = *(const float4*)&xb[2 * HW];
        float4 v3 = *(const float4*)&xb[3 * HW];
        const float* vr[4] = {(const float*)&v0, (const float*)&v1,
                              (const float*)&v2, (const float*)&v3};
#pragma unroll
        for (int q = 0; q < 4; ++q) {
            usvec4 w;
            w[0] = f2bf(vr[0][q]);
            w[1] = f2bf(vr[1][q]);
            w[2] = f2bf(vr[2][q]);
            w[3] = f2bf(vr[3][q]);
            *(usvec4*)&T[(f * 4 + q) * 72 + cg * 4] = w;
        }
        __syncthreads();
#pragma unroll
        for (int it = 0; it < 2; ++it) {
            int idx  = it * 256 + t;
            int hw_l = idx >> 3, cgo = idx & 7;
            usvec8 w = *(const usvec8*)&T[hw_l * 72 + cgo * 8];
            *(usvec8*)&xt[(size_t)(n0 + hw_l) * CIN + c0 + cgo * 8] = w;
        }
    } else if (bid < 10624) {
        // ---- pack weights to bf16 ----
        int i = (bid - 6272) * 256 + t;
        if (i < 262144) w1b[i] = f2bf(w1[i]);
        int i2 = i - 262144;
        if (i2 >= 0 && i2 < 262144) w3b[i2] = f2bf(w3[i2]);
        int i3 = i - 524288;
        if (i3 >= 0 && i3 < 589824) {
            int m = i3 / 2304, rem = i3 - m * 2304;
            int k = rem / 9, r = rem - k * 9;
            wdb[((size_t)r * P2 + m) * P1 + k] = f2bf(wd[i3]);
        }
    } else if (bid < 11408) {
        // ---- transpose perm_dconv -> permT[p][c] ----
        int p = bid - 10624;
        permT[p * P1 + t] = perm[t * HW + p];
    } else {
        // ---- zero-fill y1sp (padded planes) : 3600 blocks x 4KB ----
        int z = bid - 11408;
        usvec8 zv = {0, 0, 0, 0, 0, 0, 0, 0};
        *(usvec8*)&y1sp[((size_t)z * 256 + t) * 8] = zv;
    }
}

// ---------------- shuffle+pad via LDS: y1sp[b][pos][c] from y1c[b][c][hw] ----------------
// 512 threads: halves the serial gather loop; grid is only 256 blocks (1/CU).
__global__ __launch_bounds__(512) void shuffle_pad_kernel(const unsigned short* __restrict__ y1c,
                                                          const int* __restrict__ permT,
                                                          unsigned short* __restrict__ y1sp) {
    __shared__ unsigned short Ly[32 * 800];   // 32 channels x plane, stride 800 (16B-aligned)
    const int b  = blockIdx.x >> 3;
    const int c0 = (blockIdx.x & 7) * 32;
    const int t = threadIdx.x;
#pragma unroll
    for (int it = 0; it < 7; ++it) {
        int chunk = it * 512 + t;
        if (chunk < 3136) {
            int c = chunk / 98, off8 = (chunk - c * 98) * 8;
            usvec8 v = *(const usvec8*)&y1c[((size_t)(b * P1 + c0 + c)) * HW + off8];
            *(usvec8*)&Ly[c * 800 + off8] = v;
        }
    }
    __syncthreads();
    const int pc = t & 31, pi = t >> 5;   // 32 channels x 16 positions
    unsigned short* yb = y1sp + (size_t)b * PADHW * P1 + c0 + pc;
#pragma unroll 7
    for (int it = 0; it < 49; ++it) {
        int p = it * 16 + pi;
        int pv = permT[p * P1 + c0 + pc];
        unsigned short val = Ly[pc * 800 + pv];
        int ph = p / WIMG, pw = p - ph * WIMG;
        yb[(size_t)((ph + 1) * PADW + pw + 1) * P1] = val;
    }
}

// ---------------- conv1: y1c[b][m][hw] = relu(W1 x X) ----------------
__global__ __launch_bounds__(256) void conv1_kernel(const unsigned short* __restrict__ xt,
                                                    const unsigned short* __restrict__ w1b,
                                                    unsigned short* __restrict__ y1c) {
    __shared__ __align__(16) unsigned short As[2 * 128 * 64];
    __shared__ __align__(16) unsigned short Bs[2 * 128 * 64];
    const int m0 = blockIdx.x * 128;
    const int n0 = blockIdx.y * 128;
    const int t = threadIdx.x;
    const int lane = t & 63, wave = t >> 6;
    const int l15 = lane & 15, quad = lane >> 4;
    const int wm = wave & 1, wn = wave >> 1;
    const int grow = lane >> 3;
    const int gsw  = ((lane & 7) ^ grow) << 3;     // swizzled k-chunk (ushort offset)
    const unsigned short* Asrc[4];
    const unsigned short* Bsrc[4];
    int ldso[4];
#pragma unroll
    for (int j = 0; j < 4; ++j) {
        int q = wave * 4 + j;
        int row = (q << 3) + grow;
        Asrc[j] = w1b + (size_t)(m0 + row) * CIN + gsw;
        Bsrc[j] = xt + (size_t)(n0 + row) * CIN + gsw;
        ldso[j] = q * 512;
    }
    const int coff0 = ((quad)     ^ (l15 & 7)) << 3;
    const int coff1 = ((quad + 4) ^ (l15 & 7)) << 3;

    accvec_t acc[4][4];
    const accvec_t zero = {0.f, 0.f, 0.f, 0.f};
#pragma unroll
    for (int i = 0; i < 4; ++i)
#pragma unroll
        for (int j = 0; j < 4; ++j) acc[i][j] = zero;

    auto stage = [&](int cur, int k0) {
        unsigned short* Ab = As + cur * 8192;
        unsigned short* Bb = Bs + cur * 8192;
#pragma unroll
        for (int j = 0; j < 4; ++j) {
            GLDS16(Asrc[j] + k0, Ab + ldso[j]);
            GLDS16(Bsrc[j] + k0, Bb + ldso[j]);
        }
    };
    auto compute = [&](int cur) {
        const unsigned short* Ab = As + cur * 8192;
        const unsigned short* Bb = Bs + cur * 8192;
        bfrag_t af[4], bfr[4];
#pragma unroll
        for (int i = 0; i < 4; ++i) {
            af[i]  = *(const bfrag_t*)&Ab[(wm * 64 + i * 16 + l15) * 64 + coff0];
            bfr[i] = *(const bfrag_t*)&Bb[(wn * 64 + i * 16 + l15) * 64 + coff0];
        }
#pragma unroll
        for (int im = 0; im < 4; ++im)
#pragma unroll
            for (int in = 0; in < 4; ++in)
                acc[im][in] = __builtin_amdgcn_mfma_f32_16x16x32_bf16(af[im], bfr[in], acc[im][in], 0, 0, 0);
#pragma unroll
        for (int i = 0; i < 4; ++i) {
            af[i]  = *(const bfrag_t*)&Ab[(wm * 64 + i * 16 + l15) * 64 + coff1];
            bfr[i] = *(const bfrag_t*)&Bb[(wn * 64 + i * 16 + l15) * 64 + coff1];
        }
#pragma unroll
        for (int im = 0; im < 4; ++im)
#pragma unroll
            for (int in = 0; in < 4; ++in)
                acc[im][in] = __builtin_amdgcn_mfma_f32_16x16x32_bf16(af[im], bfr[in], acc[im][in], 0, 0, 0);
    };

    stage(0, 0);                          // prologue: tile 0 -> buf 0
    for (int s = 0; s < 16; s += 2) {
        stage(1, (s + 1) << 6);
        WAITCNT_VM(8);
        RAW_BARRIER();
        compute(0);
        RAW_BARRIER();
        if (s + 2 < 16) { stage(0, (s + 2) << 6); WAITCNT_VM(8); }
        else            { WAITCNT_VM(0); }
        RAW_BARRIER();
        compute(1);
        RAW_BARRIER();
    }
    // coalesced store: y1c[b][m][hw], hw on l15
#pragma unroll
    for (int in = 0; in < 4; ++in) {
        const int n = n0 + wn * 64 + in * 16 + l15;
        const int b = n / HW, hw = n - b * HW;
#pragma unroll
        for (int im = 0; im < 4; ++im) {
#pragma unroll
            for (int r = 0; r < 4; ++r) {
                const int m = m0 + wm * 64 + im * 16 + (quad << 2) + r;
                float v = acc[im][in][r];
                v = v > 0.f ? v : 0.f;
                y1c[((size_t)(b * P1 + m)) * HW + hw] = f2bf(v);
            }
        }
    }
}

// ======================================================================
// FUSED dconv + res_shuffle: blocks [0,392) = dconv (y1sp,wdb -> y2t),
// blocks [392,4488) = res_shuffle (x,perm_res -> res). Independent roles;
// res traffic rides dconv's idle memory pipe. LDS = shared 64KB union.
// ======================================================================
__global__ __launch_bounds__(256) void dconv_res_kernel(const unsigned short* __restrict__ y1sp,
                                                        const unsigned short* __restrict__ wdb,
                                                        unsigned short* __restrict__ y2t,
                                                        const float* __restrict__ x,
                                                        const int* __restrict__ perm_res,
                                                        unsigned short* __restrict__ res) {
    __shared__ __align__(16) unsigned char SM[65536];
    const int bid = blockIdx.x;
    const int t = threadIdx.x;
    if (bid >= 392) {
        // ---- res_shuffle: res[g][hw] = bf16(x[g][perm_res[g%CIN][hw]]) ----
        float* Lx = (float*)SM;           // 8 rows x stride 788
        const int g0 = (bid - 392) * 8;
#pragma unroll
        for (int it = 0; it < 7; ++it) {
            int chunk = it * 256 + t;
            if (chunk < 1568) {
                int r = chunk / 196, off = (chunk - r * 196) * 4;
                float4 v = *(const float4*)&x[(size_t)(g0 + r) * HW + off];
                *(float4*)&Lx[r * 788 + off] = v;
            }
        }
        __syncthreads();
        const int q0 = t & 63;
#pragma unroll
        for (int rp = 0; rp < 2; ++rp) {
            int r = rp * 4 + (t >> 6);
            int g = g0 + r;
            int m = g & (CIN - 1);
            const int* pr = perm_res + (size_t)m * HW;
#pragma unroll
            for (int it = 0; it < 13; ++it) {
                int q = it * 64 + q0;
                if (q < HW) {
                    int pv = pr[q];
                    res[(size_t)g * HW + q] = f2bf(Lx[r * 788 + pv]);
                }
            }
        }
        return;
    }
    // ---- dconv: y2t[n][m] = relu(conv3x3(y1sp, wdb)), operands swapped ----
    unsigned short* As = (unsigned short*)SM;              // 2 x 8192 ushorts
    unsigned short* Bs = (unsigned short*)(SM + 32768);    // 2 x 8192 ushorts
    const int m0 = (bid & 1) * 128;
    const int n0 = (bid >> 1) * 128;
    const int lane = t & 63, wave = t >> 6;
    const int l15 = lane & 15, quad = lane >> 4;
    const int wm = wave & 1, wn = wave >> 1;
    const int grow = lane >> 3;
    const int gsw  = ((lane & 7) ^ grow) << 3;
    const unsigned short* Asrc[4];
    const unsigned short* Bsrc[4];
    int ldso[4];
#pragma unroll
    for (int j = 0; j < 4; ++j) {
        int q = wave * 4 + j;
        int row = (q << 3) + grow;
        Asrc[j] = wdb + (size_t)(m0 + row) * P1 + gsw;
        int n = n0 + row;
        int b = n / HW, hw = n - b * HW;
        int h = hw / WIMG, w = hw - h * WIMG;
        Bsrc[j] = y1sp + ((size_t)b * PADHW + h * PADW + w) * P1 + gsw;  // top-left of 3x3 window
        ldso[j] = q * 512;
    }
    const int coff0 = ((quad)     ^ (l15 & 7)) << 3;
    const int coff1 = ((quad + 4) ^ (l15 & 7)) << 3;

    accvec_t acc[4][4];
    const accvec_t zero = {0.f, 0.f, 0.f, 0.f};
#pragma unroll
    for (int i = 0; i < 4; ++i)
#pragma unroll
        for (int j = 0; j < 4; ++j) acc[i][j] = zero;

    // 36 steps: s -> (tap r = s>>2, k0 = (s&3)*64)
    auto stage = [&](int cur, int s) {
        const int r  = s >> 2;
        const int k0 = (s & 3) << 6;
        const int kh = r / 3, kw = r - kh * 3;
        const size_t aoff = (size_t)r * (P1 * P2) + k0;
        const int    toff = (kh * PADW + kw) * P1 + k0;
        unsigned short* Ab = As + cur * 8192;
        unsigned short* Bb = Bs + cur * 8192;
#pragma unroll
        for (int j = 0; j < 4; ++j) {
            GLDS16(Asrc[j] + aoff, Ab + ldso[j]);
            GLDS16(Bsrc[j] + toff, Bb + ldso[j]);
        }
    };
    auto compute = [&](int cur) {
        const unsigned short* Ab = As + cur * 8192;
        const unsigned short* Bb = Bs + cur * 8192;
        bfrag_t af[4], bfr[4];
#pragma unroll
        for (int i = 0; i < 4; ++i) {
            af[i]  = *(const bfrag_t*)&Ab[(wm * 64 + i * 16 + l15) * 64 + coff0];
            bfr[i] = *(const bfrag_t*)&Bb[(wn * 64 + i * 16 + l15) * 64 + coff0];
        }
#pragma unroll
        for (int im = 0; im < 4; ++im)
#pragma unroll
            for (int in = 0; in < 4; ++in)
                acc[im][in] = __builtin_amdgcn_mfma_f32_16x16x32_bf16(bfr[in], af[im], acc[im][in], 0, 0, 0);
#pragma unroll
        for (int i = 0; i < 4; ++i) {
            af[i]  = *(const bfrag_t*)&Ab[(wm * 64 + i * 16 + l15) * 64 + coff1];
            bfr[i] = *(const bfrag_t*)&Bb[(wn * 64 + i * 16 + l15) * 64 + coff1];
        }
#pragma unroll
        for (int im = 0; im < 4; ++im)
#pragma unroll
            for (int in = 0; in < 4; ++in)
                acc[im][in] = __builtin_amdgcn_mfma_f32_16x16x32_bf16(bfr[in], af[im], acc[im][in], 0, 0, 0);
    };

    stage(0, 0);
    for (int s = 0; s < 36; s += 2) {
        stage(1, s + 1);                   // s+1 <= 35 always
        WAITCNT_VM(8);
        RAW_BARRIER();
        compute(0);
        RAW_BARRIER();
        if (s + 2 < 36) { stage(0, s + 2); WAITCNT_VM(8); }
        else            { WAITCNT_VM(0); }
        RAW_BARRIER();
        compute(1);
        RAW_BARRIER();
    }
    // swapped D mapping: col(l15)=m, row(quad*4+r)=n
#pragma unroll
    for (int im = 0; im < 4; ++im) {
        const int m = m0 + wm * 64 + im * 16 + l15;
#pragma unroll
        for (int in = 0; in < 4; ++in) {
#pragma unroll
            for (int r = 0; r < 4; ++r) {
                const int n = n0 + wn * 64 + in * 16 + (quad << 2) + r;
                float v = acc[im][in][r];
                v = v > 0.f ? v : 0.f;
                y2t[(size_t)n * P2 + m] = f2bf(v);
            }
        }
    }
}

// ---------------- conv3 + residual add + relu ----------------
// Double-buffered K-loop (BK=32, 8 steps) + LDS-bounce epilogue with staged
// bf16 residual (gathers must go through LDS — R3 lesson).
__global__ __launch_bounds__(256) void conv3_kernel(const unsigned short* __restrict__ y2t,
                                                    const unsigned short* __restrict__ w3b,
                                                    const unsigned short* __restrict__ res,
                                                    float* __restrict__ out) {
    __shared__ __align__(16) unsigned short SMEM[16384];  // 32KB: As[2][4096] + Bs[2][4096]; Obuf aliases
    unsigned short* AsB = SMEM;           // buffers at +0 / +4096
    unsigned short* BsB = SMEM + 8192;    // buffers at +0 / +4096
    float* Obuf = (float*)SMEM;           // 32 rows x stride 132 floats (16.9KB)

    const int m0 = blockIdx.x * 128;
    const int n0 = blockIdx.y * 128;
    const int t = threadIdx.x;
    const int lane = t & 63, wave = t >> 6;
    const int l15 = lane & 15, quad = lane >> 4;
    const int wm = wave & 1, wn = wave >> 1;
    const int srow = lane >> 2, c8 = (lane & 3) << 3;
    const int row0 = wave * 32 + srow, row1 = row0 + 16;

    const unsigned short* a0 = w3b + (size_t)(m0 + row0) * P2 + c8;
    const unsigned short* a1 = w3b + (size_t)(m0 + row1) * P2 + c8;
    const unsigned short* b0 = y2t + (size_t)(n0 + row0) * P2 + c8;
    const unsigned short* b1 = y2t + (size_t)(n0 + row1) * P2 + c8;
    const int o0 = (wave * 2 + 0) * 512, o1 = (wave * 2 + 1) * 512;

    // epilogue geometry: thread t -> (erow = t>>3, eseg = t&7); a 16-n segment
    // never crosses a batch image (784 % 16 == 0, n0 % 128 == 0).
    const int erow = t >> 3, eseg = t & 7;
    const int n_e  = n0 + eseg * 16;
    const int b_e  = n_e / HW;
    const int hw_e = n_e - b_e * HW;
    const size_t ebase0 = ((size_t)(b_e * P3 + m0 + erow)) * HW + hw_e;

    // prefetch chunk-0 residual (16 bf16 = 2 x 16B, 32B-aligned)
    usvec8 rsA = *(const usvec8*)&res[ebase0];
    usvec8 rsB = *(const usvec8*)&res[ebase0 + 8];

    accvec_t acc[4][4];
    const accvec_t zero = {0.f, 0.f, 0.f, 0.f};
#pragma unroll
    for (int i = 0; i < 4; ++i)
#pragma unroll
        for (int j = 0; j < 4; ++j) acc[i][j] = zero;

    auto stage = [&](int cur, int k0) {
        unsigned short* Ab = AsB + cur * 4096;
        unsigned short* Bb = BsB + cur * 4096;
        GLDS16(a0 + k0, Ab + o0);
        GLDS16(a1 + k0, Ab + o1);
        GLDS16(b0 + k0, Bb + o0);
        GLDS16(b1 + k0, Bb + o1);
    };
    auto compute = [&](int cur) {
        const unsigned short* Ab = AsB + cur * 4096;
        const unsigned short* Bb = BsB + cur * 4096;
        bfrag_t af[4], bfr[4];
#pragma unroll
        for (int i = 0; i < 4; ++i) {
            af[i]  = *(const bfrag_t*)&Ab[(wm * 64 + i * 16 + l15) * 32 + (quad << 3)];
            bfr[i] = *(const bfrag_t*)&Bb[(wn * 64 + i * 16 + l15) * 32 + (quad << 3)];
        }
#pragma unroll
        for (int im = 0; im < 4; ++im)
#pragma unroll
            for (int in = 0; in < 4; ++in)
                acc[im][in] = __builtin_amdgcn_mfma_f32_16x16x32_bf16(af[im], bfr[in], acc[im][in], 0, 0, 0);
    };

    stage(0, 0);
    for (int s = 0; s < 8; s += 2) {
        stage(1, (s + 1) << 5);
        WAITCNT_VM(4);
        RAW_BARRIER();
        compute(0);
        RAW_BARRIER();
        if (s + 2 < 8) { stage(0, (s + 2) << 5); WAITCNT_VM(4); }
        else           { WAITCNT_VM(0); }
        RAW_BARRIER();
        compute(1);
        RAW_BARRIER();
    }

    // ---- LDS-bounce epilogue: 4 chunks of 32 m-rows x 128 n ----
#pragma unroll
    for (int c = 0; c < 4; ++c) {
        if (wm == (c >> 1)) {
            const int imb = (c & 1) * 2;
#pragma unroll
            for (int i2 = 0; i2 < 2; ++i2)
#pragma unroll
                for (int in = 0; in < 4; ++in)
#pragma unroll
                    for (int r = 0; r < 4; ++r)
                        Obuf[(i2 * 16 + (quad << 2) + r) * 132 + wn * 64 + in * 16 + l15] =
                            acc[imb + i2][in][r];
        }
        __syncthreads();
        usvec8 nxA = rsA, nxB = rsB;
        if (c < 3) {
            const size_t nb = ebase0 + (size_t)(c + 1) * 32 * HW;
            nxA = *(const usvec8*)&res[nb];
            nxB = *(const usvec8*)&res[nb + 8];
        }
        {
            const size_t base = ebase0 + (size_t)c * 32 * HW;
            float ov[16];
#pragma unroll
            for (int q4 = 0; q4 < 4; ++q4) {
                float4 v = *(const float4*)&Obuf[erow * 132 + eseg * 16 + q4 * 4];
                ov[q4 * 4 + 0] = v.x; ov[q4 * 4 + 1] = v.y;
                ov[q4 * 4 + 2] = v.z; ov[q4 * 4 + 3] = v.w;
            }
#pragma unroll
            for (int q4 = 0; q4 < 4; ++q4) {
                float4 w;
                float e0, e1, e2, e3;
                const int j = q4 * 4;
                e0 = ov[j + 0] + bf2f((unsigned short)(j + 0 < 8 ? rsA[j + 0] : rsB[j + 0 - 8]));
                e1 = ov[j + 1] + bf2f((unsigned short)(j + 1 < 8 ? rsA[j + 1] : rsB[j + 1 - 8]));
                e2 = ov[j + 2] + bf2f((unsigned short)(j + 2 < 8 ? rsA[j + 2] : rsB[j + 2 - 8]));
                e3 = ov[j + 3] + bf2f((unsigned short)(j + 3 < 8 ? rsA[j + 3] : rsB[j + 3 - 8]));
                w.x = e0 > 0.f ? e0 : 0.f;
                w.y = e1 > 0.f ? e1 : 0.f;
                w.z = e2 > 0.f ? e2 : 0.f;
                w.w = e3 > 0.f ? e3 : 0.f;
                *(float4*)&out[base + q4 * 4] = w;
            }
        }
        rsA = nxA; rsB = nxB;
        if (c < 3) __syncthreads();   // protect Obuf before next chunk's write phase
    }
}

extern "C" void kernel_launch(void* const* d_in, const int* in_sizes, int n_in,
                              void* d_out, int out_size, void* d_ws, size_t ws_size,
                              hipStream_t stream) {
    const float* x      = (const float*)d_in[0];
    const float* w1     = (const float*)d_in[1];
    const float* wd     = (const float*)d_in[2];
    const float* w3     = (const float*)d_in[3];
    const int*   perm_d = (const int*)d_in[4];
    const int*   perm_r = (const int*)d_in[5];
    float*       out    = (float*)d_out;

    char* ws = (char*)d_ws;
    unsigned short* y1sp  = (unsigned short*)(ws + 0);         // 14,745,600
    unsigned short* y2t   = (unsigned short*)(ws + 14745600);  // 12,845,056 (also y1c — dconv overwrites after shuffle_pad consumed it)
    int*            permT = (int*)(ws + 27590656);             //    802,816
    unsigned short* w1b   = (unsigned short*)(ws + 28393472);  //    524,288
    unsigned short* wdb   = (unsigned short*)(ws + 28917760);  //  1,179,648
    unsigned short* w3b   = (unsigned short*)(ws + 30097408);  //    524,288
    unsigned short* xt    = (unsigned short*)(ws + 30621696);  // 51,380,224 (also res — res blocks of dconv_res overwrite after conv1 consumed it)
    unsigned short* resb  = xt;
    unsigned short* y1c   = y2t;

    // prep: transpose_x + pack_weights + permT + y1sp zero-fill (one dispatch)
    prep_kernel<<<dim3(15008), dim3(256), 0, stream>>>(x, xt, w1, wd, w3,
                                                       w1b, wdb, w3b,
                                                       perm_d, permT, y1sp);
    conv1_kernel<<<dim3(P1 / 128, NFLAT / 128), dim3(256), 0, stream>>>(xt, w1b, y1c);
    shuffle_pad_kernel<<<dim3(BATCH * 8), dim3(512), 0, stream>>>(y1c, permT, y1sp);
    // dconv (392 blocks) + res_shuffle (4096 blocks) fused
    dconv_res_kernel<<<dim3(392 + BATCH * CIN / 8), dim3(256), 0, stream>>>(
        y1sp, wdb, y2t, x, perm_r, resb);
    conv3_kernel<<<dim3(P3 / 128, NFLAT / 128), dim3(256), 0, stream>>>(y2t, w3b, resb, out);
}

// Round 7
// 329.044 us; speedup vs baseline: 1.1226x; 1.0075x over previous
//
#include <hip/hip_runtime.h>
#include <hip/hip_bf16.h>

// Problem constants
#define BATCH 32
#define CIN   1024
#define HW    784     // 28*28
#define WIMG  28
#define PADW  30      // padded 30x30 plane
#define PADHW 900
#define P1    256
#define P2    256
#define P3    1024
#define NFLAT (BATCH * HW)   // 25088 = 196 * 128 = 392 * 64 exactly

typedef __attribute__((ext_vector_type(8))) short bfrag_t;          // 8 bf16 (4 VGPRs)
typedef __attribute__((ext_vector_type(8))) unsigned short usvec8;
typedef __attribute__((ext_vector_type(4))) unsigned short usvec4;
typedef __attribute__((ext_vector_type(4))) float accvec_t;

static __device__ __forceinline__ unsigned short f2bf(float f) {
    union { __hip_bfloat16 h; unsigned short u; } cv;
    cv.h = __float2bfloat16(f);
    return cv.u;
}
static __device__ __forceinline__ float bf2f(unsigned short u) {
    union { float f; unsigned int i; } cv;
    cv.i = ((unsigned int)u) << 16;
    return cv.f;
}

// async 16B global->LDS DMA. LDS dest is wave-uniform base + lane*16B.
#define GLDS16(g, l) __builtin_amdgcn_global_load_lds(                      \
        (const __attribute__((address_space(1))) void*)(g),                 \
        (__attribute__((address_space(3))) void*)(l), 16, 0, 0)

// barrier WITHOUT compiler-inserted vmcnt(0) drain; pinned against code motion
#define RAW_BARRIER() do {                         \
        __builtin_amdgcn_sched_barrier(0);         \
        __builtin_amdgcn_s_barrier();              \
        __builtin_amdgcn_sched_barrier(0);         \
    } while (0)
#define WAITCNT_VM(N) do {                                        \
        asm volatile("s_waitcnt vmcnt(" #N ")" ::: "memory");     \
        __builtin_amdgcn_sched_barrier(0);                        \
    } while (0)

// ======================================================================
// PREP (fused): [0,6272) transpose_x | [6272,10624) pack_weights.
// (permT + y1sp zero-fill moved to conv1_aux window.)
// ======================================================================
__global__ __launch_bounds__(256) void prep_kernel(
        const float* __restrict__ x, unsigned short* __restrict__ xt,
        const float* __restrict__ w1, const float* __restrict__ wd,
        const float* __restrict__ w3, unsigned short* __restrict__ w1b,
        unsigned short* __restrict__ wdb, unsigned short* __restrict__ w3b) {
    __shared__ __align__(16) unsigned short T[64 * 72];   // transpose branch only
    const int bid = blockIdx.x;
    const int t   = threadIdx.x;
    if (bid < 6272) {
        // ---- transpose x -> xt[n][c] bf16 (NFLAT=392*64, no guards) ----
        const int c0 = (bid & 15) * 64;
        const int n0 = (bid >> 4) * 64;
        const int f  = t & 15;          // hw-quad: hw_local = 4f..4f+3
        const int cg = t >> 4;          // channel group: c_local = 4cg..4cg+3
        const int n  = n0 + f * 4;
        const int b  = n / HW, hw = n - b * HW;   // float4 never straddles b
        const float* xb = x + ((size_t)b * CIN + c0 + cg * 4) * HW + hw;
        float4 v0 = *(const float4*)&xb[0];
        float4 v1 = *(const float4*)&xb[HW];
        float4 v2 = *(const float4*)&xb[2 * HW];
        float4 v3 = *(const float4*)&xb[3 * HW];
        const float* vr[4] = {(const float*)&v0, (const float*)&v1,
                              (const float*)&v2, (const float*)&v3};
#pragma unroll
        for (int q = 0; q < 4; ++q) {
            usvec4 w;
            w[0] = f2bf(vr[0][q]);
            w[1] = f2bf(vr[1][q]);
            w[2] = f2bf(vr[2][q]);
            w[3] = f2bf(vr[3][q]);
            *(usvec4*)&T[(f * 4 + q) * 72 + cg * 4] = w;
        }
        __syncthreads();
#pragma unroll
        for (int it = 0; it < 2; ++it) {
            int idx  = it * 256 + t;
            int hw_l = idx >> 3, cgo = idx & 7;
            usvec8 w = *(const usvec8*)&T[hw_l * 72 + cgo * 8];
            *(usvec8*)&xt[(size_t)(n0 + hw_l) * CIN + c0 + cgo * 8] = w;
        }
    } else {
        // ---- pack weights to bf16 ----
        int i = (bid - 6272) * 256 + t;
        if (i < 262144) w1b[i] = f2bf(w1[i]);
        int i2 = i - 262144;
        if (i2 >= 0 && i2 < 262144) w3b[i2] = f2bf(w3[i2]);
        int i3 = i - 524288;
        if (i3 >= 0 && i3 < 589824) {
            int m = i3 / 2304, rem = i3 - m * 2304;
            int k = rem / 9, r = rem - k * 9;
            wdb[((size_t)r * P2 + m) * P1 + k] = f2bf(wd[i3]);
        }
    }
}

// ---------------- shuffle+pad via LDS: y1sp[b][pos][c] from y1c[b][c][hw] ----------------
// 512 threads: halves the serial gather loop; grid is only 256 blocks (1/CU).
__global__ __launch_bounds__(512) void shuffle_pad_kernel(const unsigned short* __restrict__ y1c,
                                                          const int* __restrict__ permT,
                                                          unsigned short* __restrict__ y1sp) {
    __shared__ unsigned short Ly[32 * 800];   // 32 channels x plane, stride 800 (16B-aligned)
    const int b  = blockIdx.x >> 3;
    const int c0 = (blockIdx.x & 7) * 32;
    const int t = threadIdx.x;
#pragma unroll
    for (int it = 0; it < 7; ++it) {
        int chunk = it * 512 + t;
        if (chunk < 3136) {
            int c = chunk / 98, off8 = (chunk - c * 98) * 8;
            usvec8 v = *(const usvec8*)&y1c[((size_t)(b * P1 + c0 + c)) * HW + off8];
            *(usvec8*)&Ly[c * 800 + off8] = v;
        }
    }
    __syncthreads();
    const int pc = t & 31, pi = t >> 5;   // 32 channels x 16 positions
    unsigned short* yb = y1sp + (size_t)b * PADHW * P1 + c0 + pc;
#pragma unroll 7
    for (int it = 0; it < 49; ++it) {
        int p = it * 16 + pi;
        int pv = permT[p * P1 + c0 + pc];
        unsigned short val = Ly[pc * 800 + pv];
        int ph = p / WIMG, pw = p - ph * WIMG;
        yb[(size_t)((ph + 1) * PADW + pw + 1) * P1] = val;
    }
}

// ======================================================================
// conv1 + aux: [0,392) = conv1 GEMM (XCD-swizzled), [392,1176) = permT
// transpose, [1176,4776) = y1sp zero-fill. Aux work (needed only by
// shuffle_pad/dconv) rides conv1's latency-bound window. 4776 % 8 == 0.
// ======================================================================
__global__ __launch_bounds__(256) void conv1_aux_kernel(
        const unsigned short* __restrict__ xt, const unsigned short* __restrict__ w1b,
        unsigned short* __restrict__ y1c,
        const int* __restrict__ perm, int* __restrict__ permT,
        unsigned short* __restrict__ y1sp) {
    __shared__ __align__(16) unsigned short As[2 * 128 * 64];
    __shared__ __align__(16) unsigned short Bs[2 * 128 * 64];
    const int bid = blockIdx.x;
    const int t = threadIdx.x;
    if (bid >= 1176) {
        // ---- zero-fill y1sp: 3600 blocks x 4KB ----
        int z = bid - 1176;
        usvec8 zv = {0, 0, 0, 0, 0, 0, 0, 0};
        *(usvec8*)&y1sp[((size_t)z * 256 + t) * 8] = zv;
        return;
    }
    if (bid >= 392) {
        // ---- transpose perm_dconv -> permT[p][c] ----
        int p = bid - 392;
        permT[p * P1 + t] = perm[t * HW + p];
        return;
    }
    // ---- conv1 GEMM, XCD-bijective swizzle (392 = 8*49): blocks sharing a
    // B-panel (same/adjacent n) land on the same XCD's L2.
    const int l = (bid & 7) * 49 + (bid >> 3);
    const int m0 = (l & 1) * 128;
    const int n0 = (l >> 1) * 128;
    const int lane = t & 63, wave = t >> 6;
    const int l15 = lane & 15, quad = lane >> 4;
    const int wm = wave & 1, wn = wave >> 1;
    const int grow = lane >> 3;
    const int gsw  = ((lane & 7) ^ grow) << 3;     // swizzled k-chunk (ushort offset)
    const unsigned short* Asrc[4];
    const unsigned short* Bsrc[4];
    int ldso[4];
#pragma unroll
    for (int j = 0; j < 4; ++j) {
        int q = wave * 4 + j;
        int row = (q << 3) + grow;
        Asrc[j] = w1b + (size_t)(m0 + row) * CIN + gsw;
        Bsrc[j] = xt + (size_t)(n0 + row) * CIN + gsw;
        ldso[j] = q * 512;
    }
    const int coff0 = ((quad)     ^ (l15 & 7)) << 3;
    const int coff1 = ((quad + 4) ^ (l15 & 7)) << 3;

    accvec_t acc[4][4];
    const accvec_t zero = {0.f, 0.f, 0.f, 0.f};
#pragma unroll
    for (int i = 0; i < 4; ++i)
#pragma unroll
        for (int j = 0; j < 4; ++j) acc[i][j] = zero;

    auto stage = [&](int cur, int k0) {
        unsigned short* Ab = As + cur * 8192;
        unsigned short* Bb = Bs + cur * 8192;
#pragma unroll
        for (int j = 0; j < 4; ++j) {
            GLDS16(Asrc[j] + k0, Ab + ldso[j]);
            GLDS16(Bsrc[j] + k0, Bb + ldso[j]);
        }
    };
    auto compute = [&](int cur) {
        const unsigned short* Ab = As + cur * 8192;
        const unsigned short* Bb = Bs + cur * 8192;
        bfrag_t af[4], bfr[4];
#pragma unroll
        for (int i = 0; i < 4; ++i) {
            af[i]  = *(const bfrag_t*)&Ab[(wm * 64 + i * 16 + l15) * 64 + coff0];
            bfr[i] = *(const bfrag_t*)&Bb[(wn * 64 + i * 16 + l15) * 64 + coff0];
        }
#pragma unroll
        for (int im = 0; im < 4; ++im)
#pragma unroll
            for (int in = 0; in < 4; ++in)
                acc[im][in] = __builtin_amdgcn_mfma_f32_16x16x32_bf16(af[im], bfr[in], acc[im][in], 0, 0, 0);
#pragma unroll
        for (int i = 0; i < 4; ++i) {
            af[i]  = *(const bfrag_t*)&Ab[(wm * 64 + i * 16 + l15) * 64 + coff1];
            bfr[i] = *(const bfrag_t*)&Bb[(wn * 64 + i * 16 + l15) * 64 + coff1];
        }
#pragma unroll
        for (int im = 0; im < 4; ++im)
#pragma unroll
            for (int in = 0; in < 4; ++in)
                acc[im][in] = __builtin_amdgcn_mfma_f32_16x16x32_bf16(af[im], bfr[in], acc[im][in], 0, 0, 0);
    };

    stage(0, 0);                          // prologue: tile 0 -> buf 0
    for (int s = 0; s < 16; s += 2) {
        stage(1, (s + 1) << 6);
        WAITCNT_VM(8);
        RAW_BARRIER();
        compute(0);
        RAW_BARRIER();
        if (s + 2 < 16) { stage(0, (s + 2) << 6); WAITCNT_VM(8); }
        else            { WAITCNT_VM(0); }
        RAW_BARRIER();
        compute(1);
        RAW_BARRIER();
    }
    // coalesced store: y1c[b][m][hw], hw on l15
#pragma unroll
    for (int in = 0; in < 4; ++in) {
        const int n = n0 + wn * 64 + in * 16 + l15;
        const int b = n / HW, hw = n - b * HW;
#pragma unroll
        for (int im = 0; im < 4; ++im) {
#pragma unroll
            for (int r = 0; r < 4; ++r) {
                const int m = m0 + wm * 64 + im * 16 + (quad << 2) + r;
                float v = acc[im][in][r];
                v = v > 0.f ? v : 0.f;
                y1c[((size_t)(b * P1 + m)) * HW + hw] = f2bf(v);
            }
        }
    }
}

// ======================================================================
// FUSED dconv + res_shuffle: blocks [0,392) = dconv (XCD-swizzled),
// blocks [392,4488) = res_shuffle. res traffic rides dconv's idle pipes.
// ======================================================================
__global__ __launch_bounds__(256) void dconv_res_kernel(const unsigned short* __restrict__ y1sp,
                                                        const unsigned short* __restrict__ wdb,
                                                        unsigned short* __restrict__ y2t,
                                                        const float* __restrict__ x,
                                                        const int* __restrict__ perm_res,
                                                        unsigned short* __restrict__ res) {
    __shared__ __align__(16) unsigned char SM[65536];
    const int bid = blockIdx.x;
    const int t = threadIdx.x;
    if (bid >= 392) {
        // ---- res_shuffle: res[g][hw] = bf16(x[g][perm_res[g%CIN][hw]]) ----
        float* Lx = (float*)SM;           // 8 rows x stride 788
        const int g0 = (bid - 392) * 8;
#pragma unroll
        for (int it = 0; it < 7; ++it) {
            int chunk = it * 256 + t;
            if (chunk < 1568) {
                int r = chunk / 196, off = (chunk - r * 196) * 4;
                float4 v = *(const float4*)&x[(size_t)(g0 + r) * HW + off];
                *(float4*)&Lx[r * 788 + off] = v;
            }
        }
        __syncthreads();
        const int q0 = t & 63;
#pragma unroll
        for (int rp = 0; rp < 2; ++rp) {
            int r = rp * 4 + (t >> 6);
            int g = g0 + r;
            int m = g & (CIN - 1);
            const int* pr = perm_res + (size_t)m * HW;
#pragma unroll
            for (int it = 0; it < 13; ++it) {
                int q = it * 64 + q0;
                if (q < HW) {
                    int pv = pr[q];
                    res[(size_t)g * HW + q] = f2bf(Lx[r * 788 + pv]);
                }
            }
        }
        return;
    }
    // ---- dconv GEMM, XCD-bijective swizzle (392 = 8*49): same-n pairs and
    // vertical-halo neighbor n-tiles share the XCD's L2.
    unsigned short* As = (unsigned short*)SM;              // 2 x 8192 ushorts
    unsigned short* Bs = (unsigned short*)(SM + 32768);    // 2 x 8192 ushorts
    const int l = (bid & 7) * 49 + (bid >> 3);
    const int m0 = (l & 1) * 128;
    const int n0 = (l >> 1) * 128;
    const int lane = t & 63, wave = t >> 6;
    const int l15 = lane & 15, quad = lane >> 4;
    const int wm = wave & 1, wn = wave >> 1;
    const int grow = lane >> 3;
    const int gsw  = ((lane & 7) ^ grow) << 3;
    const unsigned short* Asrc[4];
    const unsigned short* Bsrc[4];
    int ldso[4];
#pragma unroll
    for (int j = 0; j < 4; ++j) {
        int q = wave * 4 + j;
        int row = (q << 3) + grow;
        Asrc[j] = wdb + (size_t)(m0 + row) * P1 + gsw;
        int n = n0 + row;
        int b = n / HW, hw = n - b * HW;
        int h = hw / WIMG, w = hw - h * WIMG;
        Bsrc[j] = y1sp + ((size_t)b * PADHW + h * PADW + w) * P1 + gsw;  // top-left of 3x3 window
        ldso[j] = q * 512;
    }
    const int coff0 = ((quad)     ^ (l15 & 7)) << 3;
    const int coff1 = ((quad + 4) ^ (l15 & 7)) << 3;

    accvec_t acc[4][4];
    const accvec_t zero = {0.f, 0.f, 0.f, 0.f};
#pragma unroll
    for (int i = 0; i < 4; ++i)
#pragma unroll
        for (int j = 0; j < 4; ++j) acc[i][j] = zero;

    // 36 steps: s -> (tap r = s>>2, k0 = (s&3)*64)
    auto stage = [&](int cur, int s) {
        const int r  = s >> 2;
        const int k0 = (s & 3) << 6;
        const int kh = r / 3, kw = r - kh * 3;
        const size_t aoff = (size_t)r * (P1 * P2) + k0;
        const int    toff = (kh * PADW + kw) * P1 + k0;
        unsigned short* Ab = As + cur * 8192;
        unsigned short* Bb = Bs + cur * 8192;
#pragma unroll
        for (int j = 0; j < 4; ++j) {
            GLDS16(Asrc[j] + aoff, Ab + ldso[j]);
            GLDS16(Bsrc[j] + toff, Bb + ldso[j]);
        }
    };
    auto compute = [&](int cur) {
        const unsigned short* Ab = As + cur * 8192;
        const unsigned short* Bb = Bs + cur * 8192;
        bfrag_t af[4], bfr[4];
#pragma unroll
        for (int i = 0; i < 4; ++i) {
            af[i]  = *(const bfrag_t*)&Ab[(wm * 64 + i * 16 + l15) * 64 + coff0];
            bfr[i] = *(const bfrag_t*)&Bb[(wn * 64 + i * 16 + l15) * 64 + coff0];
        }
#pragma unroll
        for (int im = 0; im < 4; ++im)
#pragma unroll
            for (int in = 0; in < 4; ++in)
                acc[im][in] = __builtin_amdgcn_mfma_f32_16x16x32_bf16(bfr[in], af[im], acc[im][in], 0, 0, 0);
#pragma unroll
        for (int i = 0; i < 4; ++i) {
            af[i]  = *(const bfrag_t*)&Ab[(wm * 64 + i * 16 + l15) * 64 + coff1];
            bfr[i] = *(const bfrag_t*)&Bb[(wn * 64 + i * 16 + l15) * 64 + coff1];
        }
#pragma unroll
        for (int im = 0; im < 4; ++im)
#pragma unroll
            for (int in = 0; in < 4; ++in)
                acc[im][in] = __builtin_amdgcn_mfma_f32_16x16x32_bf16(bfr[in], af[im], acc[im][in], 0, 0, 0);
    };

    stage(0, 0);
    for (int s = 0; s < 36; s += 2) {
        stage(1, s + 1);                   // s+1 <= 35 always
        WAITCNT_VM(8);
        RAW_BARRIER();
        compute(0);
        RAW_BARRIER();
        if (s + 2 < 36) { stage(0, s + 2); WAITCNT_VM(8); }
        else            { WAITCNT_VM(0); }
        RAW_BARRIER();
        compute(1);
        RAW_BARRIER();
    }
    // swapped D mapping: col(l15)=m, row(quad*4+r)=n
#pragma unroll
    for (int im = 0; im < 4; ++im) {
        const int m = m0 + wm * 64 + im * 16 + l15;
#pragma unroll
        for (int in = 0; in < 4; ++in) {
#pragma unroll
            for (int r = 0; r < 4; ++r) {
                const int n = n0 + wn * 64 + in * 16 + (quad << 2) + r;
                float v = acc[im][in][r];
                v = v > 0.f ? v : 0.f;
                y2t[(size_t)n * P2 + m] = f2bf(v);
            }
        }
    }
}

// ---------------- conv3 + residual add + relu ----------------
// Double-buffered K-loop + LDS-bounce epilogue; 1-D grid with XCD-bijective
// swizzle (1568 = 8*196) so the 8 m-blocks sharing a y2t B-panel run on the
// same XCD (panel L2-hot instead of re-pulled from L3 per XCD).
__global__ __launch_bounds__(256) void conv3_kernel(const unsigned short* __restrict__ y2t,
                                                    const unsigned short* __restrict__ w3b,
                                                    const unsigned short* __restrict__ res,
                                                    float* __restrict__ out) {
    __shared__ __align__(16) unsigned short SMEM[16384];  // 32KB: As[2][4096] + Bs[2][4096]; Obuf aliases
    unsigned short* AsB = SMEM;           // buffers at +0 / +4096
    unsigned short* BsB = SMEM + 8192;    // buffers at +0 / +4096
    float* Obuf = (float*)SMEM;           // 32 rows x stride 132 floats (16.9KB)

    const int bid = blockIdx.x;
    const int l  = (bid & 7) * 196 + (bid >> 3);   // bijective: 1568 = 8*196
    const int m0 = (l & 7) * 128;
    const int n0 = (l >> 3) * 128;
    const int t = threadIdx.x;
    const int lane = t & 63, wave = t >> 6;
    const int l15 = lane & 15, quad = lane >> 4;
    const int wm = wave & 1, wn = wave >> 1;
    const int srow = lane >> 2, c8 = (lane & 3) << 3;
    const int row0 = wave * 32 + srow, row1 = row0 + 16;

    const unsigned short* a0 = w3b + (size_t)(m0 + row0) * P2 + c8;
    const unsigned short* a1 = w3b + (size_t)(m0 + row1) * P2 + c8;
    const unsigned short* b0 = y2t + (size_t)(n0 + row0) * P2 + c8;
    const unsigned short* b1 = y2t + (size_t)(n0 + row1) * P2 + c8;
    const int o0 = (wave * 2 + 0) * 512, o1 = (wave * 2 + 1) * 512;

    // epilogue geometry: thread t -> (erow = t>>3, eseg = t&7); a 16-n segment
    // never crosses a batch image (784 % 16 == 0, n0 % 128 == 0).
    const int erow = t >> 3, eseg = t & 7;
    const int n_e  = n0 + eseg * 16;
    const int b_e  = n_e / HW;
    const int hw_e = n_e - b_e * HW;
    const size_t ebase0 = ((size_t)(b_e * P3 + m0 + erow)) * HW + hw_e;

    // prefetch chunk-0 residual (16 bf16 = 2 x 16B, 32B-aligned)
    usvec8 rsA = *(const usvec8*)&res[ebase0];
    usvec8 rsB = *(const usvec8*)&res[ebase0 + 8];

    accvec_t acc[4][4];
    const accvec_t zero = {0.f, 0.f, 0.f, 0.f};
#pragma unroll
    for (int i = 0; i < 4; ++i)
#pragma unroll
        for (int j = 0; j < 4; ++j) acc[i][j] = zero;

    auto stage = [&](int cur, int k0) {
        unsigned short* Ab = AsB + cur * 4096;
        unsigned short* Bb = BsB + cur * 4096;
        GLDS16(a0 + k0, Ab + o0);
        GLDS16(a1 + k0, Ab + o1);
        GLDS16(b0 + k0, Bb + o0);
        GLDS16(b1 + k0, Bb + o1);
    };
    auto compute = [&](int cur) {
        const unsigned short* Ab = AsB + cur * 4096;
        const unsigned short* Bb = BsB + cur * 4096;
        bfrag_t af[4], bfr[4];
#pragma unroll
        for (int i = 0; i < 4; ++i) {
            af[i]  = *(const bfrag_t*)&Ab[(wm * 64 + i * 16 + l15) * 32 + (quad << 3)];
            bfr[i] = *(const bfrag_t*)&Bb[(wn * 64 + i * 16 + l15) * 32 + (quad << 3)];
        }
#pragma unroll
        for (int im = 0; im < 4; ++im)
#pragma unroll
            for (int in = 0; in < 4; ++in)
                acc[im][in] = __builtin_amdgcn_mfma_f32_16x16x32_bf16(af[im], bfr[in], acc[im][in], 0, 0, 0);
    };

    stage(0, 0);
    for (int s = 0; s < 8; s += 2) {
        stage(1, (s + 1) << 5);
        WAITCNT_VM(4);
        RAW_BARRIER();
        compute(0);
        RAW_BARRIER();
        if (s + 2 < 8) { stage(0, (s + 2) << 5); WAITCNT_VM(4); }
        else           { WAITCNT_VM(0); }
        RAW_BARRIER();
        compute(1);
        RAW_BARRIER();
    }

    // ---- LDS-bounce epilogue: 4 chunks of 32 m-rows x 128 n ----
#pragma unroll
    for (int c = 0; c < 4; ++c) {
        if (wm == (c >> 1)) {
            const int imb = (c & 1) * 2;
#pragma unroll
            for (int i2 = 0; i2 < 2; ++i2)
#pragma unroll
                for (int in = 0; in < 4; ++in)
#pragma unroll
                    for (int r = 0; r < 4; ++r)
                        Obuf[(i2 * 16 + (quad << 2) + r) * 132 + wn * 64 + in * 16 + l15] =
                            acc[imb + i2][in][r];
        }
        __syncthreads();
        usvec8 nxA = rsA, nxB = rsB;
        if (c < 3) {
            const size_t nb = ebase0 + (size_t)(c + 1) * 32 * HW;
            nxA = *(const usvec8*)&res[nb];
            nxB = *(const usvec8*)&res[nb + 8];
        }
        {
            const size_t base = ebase0 + (size_t)c * 32 * HW;
            float ov[16];
#pragma unroll
            for (int q4 = 0; q4 < 4; ++q4) {
                float4 v = *(const float4*)&Obuf[erow * 132 + eseg * 16 + q4 * 4];
                ov[q4 * 4 + 0] = v.x; ov[q4 * 4 + 1] = v.y;
                ov[q4 * 4 + 2] = v.z; ov[q4 * 4 + 3] = v.w;
            }
#pragma unroll
            for (int q4 = 0; q4 < 4; ++q4) {
                float4 w;
                float e0, e1, e2, e3;
                const int j = q4 * 4;
                e0 = ov[j + 0] + bf2f((unsigned short)(j + 0 < 8 ? rsA[j + 0] : rsB[j + 0 - 8]));
                e1 = ov[j + 1] + bf2f((unsigned short)(j + 1 < 8 ? rsA[j + 1] : rsB[j + 1 - 8]));
                e2 = ov[j + 2] + bf2f((unsigned short)(j + 2 < 8 ? rsA[j + 2] : rsB[j + 2 - 8]));
                e3 = ov[j + 3] + bf2f((unsigned short)(j + 3 < 8 ? rsA[j + 3] : rsB[j + 3 - 8]));
                w.x = e0 > 0.f ? e0 : 0.f;
                w.y = e1 > 0.f ? e1 : 0.f;
                w.z = e2 > 0.f ? e2 : 0.f;
                w.w = e3 > 0.f ? e3 : 0.f;
                *(float4*)&out[base + q4 * 4] = w;
            }
        }
        rsA = nxA; rsB = nxB;
        if (c < 3) __syncthreads();   // protect Obuf before next chunk's write phase
    }
}

extern "C" void kernel_launch(void* const* d_in, const int* in_sizes, int n_in,
                              void* d_out, int out_size, void* d_ws, size_t ws_size,
                              hipStream_t stream) {
    const float* x      = (const float*)d_in[0];
    const float* w1     = (const float*)d_in[1];
    const float* wd     = (const float*)d_in[2];
    const float* w3     = (const float*)d_in[3];
    const int*   perm_d = (const int*)d_in[4];
    const int*   perm_r = (const int*)d_in[5];
    float*       out    = (float*)d_out;

    char* ws = (char*)d_ws;
    unsigned short* y1sp  = (unsigned short*)(ws + 0);         // 14,745,600
    unsigned short* y2t   = (unsigned short*)(ws + 14745600);  // 12,845,056 (also y1c — dconv overwrites after shuffle_pad consumed it)
    int*            permT = (int*)(ws + 27590656);             //    802,816
    unsigned short* w1b   = (unsigned short*)(ws + 28393472);  //    524,288
    unsigned short* wdb   = (unsigned short*)(ws + 28917760);  //  1,179,648
    unsigned short* w3b   = (unsigned short*)(ws + 30097408);  //    524,288
    unsigned short* xt    = (unsigned short*)(ws + 30621696);  // 51,380,224 (also res — res blocks of dconv_res overwrite after conv1 consumed it)
    unsigned short* resb  = xt;
    unsigned short* y1c   = y2t;

    // prep: transpose_x + pack_weights (one dispatch)
    prep_kernel<<<dim3(10624), dim3(256), 0, stream>>>(x, xt, w1, wd, w3,
                                                       w1b, wdb, w3b);
    // conv1 (392, XCD-swizzled) + permT (784) + y1sp zero-fill (3600)
    conv1_aux_kernel<<<dim3(4776), dim3(256), 0, stream>>>(xt, w1b, y1c,
                                                           perm_d, permT, y1sp);
    shuffle_pad_kernel<<<dim3(BATCH * 8), dim3(512), 0, stream>>>(y1c, permT, y1sp);
    // dconv (392, XCD-swizzled) + res_shuffle (4096) fused
    dconv_res_kernel<<<dim3(392 + BATCH * CIN / 8), dim3(256), 0, stream>>>(
        y1sp, wdb, y2t, x, perm_r, resb);
    conv3_kernel<<<dim3(1568), dim3(256), 0, stream>>>(y2t, w3b, resb, out);
}